// Round 1
// baseline (1996.093 us; speedup 1.0000x reference)
//
#include <hip/hip_runtime.h>

#define N_NODES 20000
#define N_EDGES 160000
#define EP (N_EDGES + N_NODES)   // 180000 edges incl. self loops

__device__ __forceinline__ float bcast(float v, int k) {
  return __uint_as_float(__builtin_amdgcn_readlane(__float_as_uint(v), k));
}

__device__ __forceinline__ float wave_reduce_sum(float v) {
#pragma unroll
  for (int o = 32; o > 0; o >>= 1) v += __shfl_down(v, o, 64);
  return v;
}

__device__ __forceinline__ float wave_reduce_max(float v) {
#pragma unroll
  for (int o = 32; o > 0; o >>= 1) v = fmaxf(v, __shfl_down(v, o, 64));
  return v;
}

// ---------------- CSR build ----------------

__global__ void k_zero(int* __restrict__ cnt, int* __restrict__ fill) {
  int i = blockIdx.x * blockDim.x + threadIdx.x;
  if (i < N_NODES) { cnt[i] = 0; fill[i] = 0; }
}

__global__ void k_count(const int* __restrict__ dst, int* __restrict__ cnt) {
  int i = blockIdx.x * blockDim.x + threadIdx.x;
  if (i < N_EDGES) atomicAdd(&cnt[dst[i]], 1);
}

__global__ void k_scan(const int* __restrict__ cnt, int* __restrict__ row_ptr) {
  __shared__ int sh[1024];
  __shared__ int carry;
  int tid = threadIdx.x;
  if (tid == 0) { carry = 0; row_ptr[0] = 0; }
  __syncthreads();
  for (int base = 0; base < N_NODES; base += 1024) {
    int i = base + tid;
    int v = (i < N_NODES) ? (cnt[i] + 1) : 0;  // +1 self loop
    sh[tid] = v;
    __syncthreads();
#pragma unroll
    for (int off = 1; off < 1024; off <<= 1) {
      int t = (tid >= off) ? sh[tid - off] : 0;
      __syncthreads();
      sh[tid] += t;
      __syncthreads();
    }
    int rp = carry + sh[tid];
    if (i < N_NODES) row_ptr[i + 1] = rp;
    __syncthreads();
    if (tid == 1023) carry += sh[1023];
    __syncthreads();
  }
}

__global__ void k_scatter(const int* __restrict__ dst, const int* __restrict__ row_ptr,
                          int* __restrict__ fill, int* __restrict__ col_idx) {
  int i = blockIdx.x * blockDim.x + threadIdx.x;
  if (i >= EP) return;
  int d = (i < N_EDGES) ? dst[i] : (i - N_EDGES);
  int p = row_ptr[d] + atomicAdd(&fill[d], 1);
  col_idx[p] = i;
}

__global__ void k_sort(const int* __restrict__ row_ptr, int* __restrict__ col_idx) {
  int n = blockIdx.x * blockDim.x + threadIdx.x;
  if (n >= N_NODES) return;
  int s = row_ptr[n], e = row_ptr[n + 1];
  for (int i = s + 1; i < e; ++i) {
    int v = col_idx[i];
    int j = i - 1;
    while (j >= s && col_idx[j] > v) { col_idx[j + 1] = col_idx[j]; --j; }
    col_idx[j + 1] = v;
  }
}

// ---------------- encoders ----------------

__global__ __launch_bounds__(256) void k_node_enc(
    const float* __restrict__ x, const float* __restrict__ w1, const float* __restrict__ b1,
    const float* __restrict__ w2, const float* __restrict__ b2, float* __restrict__ h) {
  __shared__ float w2l[4096];
  int tid = threadIdx.x;
#pragma unroll
  for (int q = 0; q < 16; ++q) w2l[q * 256 + tid] = w2[q * 256 + tid];
  __syncthreads();
  int lane = tid & 63, g = tid >> 6;
  int n = blockIdx.x * 4 + g;
  float x0 = x[n * 2], x1 = x[n * 2 + 1];
  float hid = fmaxf(x0 * w1[lane] + x1 * w1[64 + lane] + b1[lane], 0.f);
  float out = b2[lane];
#pragma unroll
  for (int k = 0; k < 64; ++k) out += bcast(hid, k) * w2l[k * 64 + lane];
  h[n * 64 + lane] = out;
}

__global__ __launch_bounds__(256) void k_edge_enc(
    const float* __restrict__ ea, const float* __restrict__ w1, const float* __restrict__ b1,
    const float* __restrict__ w2, const float* __restrict__ b2, float* __restrict__ ef) {
  __shared__ float w2l[4096];
  int tid = threadIdx.x;
#pragma unroll
  for (int q = 0; q < 16; ++q) w2l[q * 256 + tid] = w2[q * 256 + tid];
  __syncthreads();
  int lane = tid & 63, g = tid >> 6;
  int i = blockIdx.x * 4 + g;
  float a0 = ea[i * 3], a1 = ea[i * 3 + 1], a2 = ea[i * 3 + 2];
  float hid = fmaxf(a0 * w1[lane] + a1 * w1[64 + lane] + a2 * w1[128 + lane] + b1[lane], 0.f);
  float out = b2[lane];
#pragma unroll
  for (int k = 0; k < 64; ++k) out += bcast(hid, k) * w2l[k * 64 + lane];
  ef[i * 64 + lane] = out;
}

// self-loop edge features: mean of incoming original-edge features (deterministic via CSR)
__global__ __launch_bounds__(256) void k_loop_feat(
    const int* __restrict__ row_ptr, const int* __restrict__ col_idx, float* __restrict__ ef) {
  int tid = threadIdx.x, lane = tid & 63, g = tid >> 6;
  int n = blockIdx.x * 4 + g;
  int s = row_ptr[n], e = row_ptr[n + 1];
  float acc = 0.f;
  for (int i = s; i < e; ++i) {
    int eid = col_idx[i];
    if (eid < N_EDGES) acc += ef[eid * 64 + lane];
  }
  int c = e - s - 1;  // original in-degree
  ef[(N_EDGES + n) * 64 + lane] = acc / (float)(c > 0 ? c : 1);
}

// ---------------- GAT layer ----------------

// out[n][j] = bias[j] + sum_k h[n][k] * W[k][j]   (W: [64,256])
__global__ __launch_bounds__(256) void k_xlr(
    const float* __restrict__ h, const float* __restrict__ W,
    const float* __restrict__ bias, float* __restrict__ out) {
  __shared__ float Wl[64 * 256];
  int tid = threadIdx.x;
#pragma unroll
  for (int r = 0; r < 64; ++r) Wl[r * 256 + tid] = W[r * 256 + tid];
  __syncthreads();
  int lane = tid & 63;
  float bv = bias[tid];
  const int NT = N_NODES / 8;  // 2500 tiles of 8 nodes
  for (int tile = blockIdx.x; tile < NT; tile += gridDim.x) {
    int n0 = tile * 8;
    float hreg[8], acc[8];
#pragma unroll
    for (int t = 0; t < 8; ++t) { hreg[t] = h[(n0 + t) * 64 + lane]; acc[t] = bv; }
#pragma unroll
    for (int k = 0; k < 64; ++k) {
      float w = Wl[k * 256 + tid];
#pragma unroll
      for (int t = 0; t < 8; ++t) acc[t] += bcast(hreg[t], k) * w;
    }
#pragma unroll
    for (int t = 0; t < 8; ++t) out[(n0 + t) * 256 + tid] = acc[t];
  }
}

// per edge: ee = e_f[e]@we ; m = leaky(xl[src]+xr[dst]+ee) ; logits[e][h] = <m[h,:],att[h,:]>
__global__ __launch_bounds__(256) void k_edge_logits(
    const float* __restrict__ xl, const float* __restrict__ xr,
    const float* __restrict__ ef, const int* __restrict__ src, const int* __restrict__ dst,
    const float* __restrict__ we, const float* __restrict__ att, float* __restrict__ logits) {
  __shared__ float Wl[64 * 256];
  int tid = threadIdx.x;
#pragma unroll
  for (int r = 0; r < 64; ++r) Wl[r * 256 + tid] = we[r * 256 + tid];
  __syncthreads();
  int lane = tid & 63, hw = tid >> 6;
  float av = att[tid];
  int base = blockIdx.x * 16;
#pragma unroll 1
  for (int e0 = 0; e0 < 16; e0 += 4) {
    float efr[4], g[4], acc[4];
#pragma unroll
    for (int t = 0; t < 4; ++t) {
      int eid = base + e0 + t;
      int s, d;
      if (eid < N_EDGES) { s = src[eid]; d = dst[eid]; }
      else { s = d = eid - N_EDGES; }
      efr[t] = ef[eid * 64 + lane];
      g[t] = xl[s * 256 + tid] + xr[d * 256 + tid];
      acc[t] = 0.f;
    }
#pragma unroll
    for (int k = 0; k < 64; ++k) {
      float w = Wl[k * 256 + tid];
      acc[0] += bcast(efr[0], k) * w;
      acc[1] += bcast(efr[1], k) * w;
      acc[2] += bcast(efr[2], k) * w;
      acc[3] += bcast(efr[3], k) * w;
    }
#pragma unroll
    for (int t = 0; t < 4; ++t) {
      float mm = g[t] + acc[t];
      mm = mm > 0.f ? mm : 0.2f * mm;
      float p = wave_reduce_sum(mm * av);
      if (lane == 0) logits[(base + e0 + t) * 4 + hw] = p;
    }
  }
}

// segment softmax + aggregation + mean over heads + bias + relu + residual, per dst node
__global__ __launch_bounds__(256) void k_node_agg(
    const float* __restrict__ xl, const float* __restrict__ logits,
    const int* __restrict__ row_ptr, const int* __restrict__ col_idx,
    const int* __restrict__ src, const float* __restrict__ bias, float* __restrict__ h) {
  __shared__ float mxs[4], ssum[4], sm[256];
  int tid = threadIdx.x, lane = tid & 63, hw = tid >> 6;
  int n = blockIdx.x;
  int s0 = row_ptr[n], s1 = row_ptr[n + 1];
  float m = -3.4e38f;
  for (int i = s0 + lane; i < s1; i += 64) m = fmaxf(m, logits[col_idx[i] * 4 + hw]);
  m = wave_reduce_max(m);
  if (lane == 0) mxs[hw] = m;
  __syncthreads();
  float mx = mxs[hw];
  float sum = 0.f;
  for (int i = s0 + lane; i < s1; i += 64) sum += __expf(logits[col_idx[i] * 4 + hw] - mx);
  sum = wave_reduce_sum(sum);
  if (lane == 0) ssum[hw] = sum;
  __syncthreads();
  float inv = 1.f / ssum[hw];
  float acc = 0.f;
  for (int i = s0; i < s1; ++i) {
    int eid = col_idx[i];
    int sn = (eid < N_EDGES) ? src[eid] : n;
    float al = __expf(logits[eid * 4 + hw] - mx) * inv;
    acc += al * xl[sn * 256 + tid];
  }
  sm[tid] = acc;
  __syncthreads();
  if (tid < 64) {
    float v = 0.25f * (sm[tid] + sm[tid + 64] + sm[tid + 128] + sm[tid + 192]) + bias[tid];
    h[n * 64 + tid] += fmaxf(v, 0.f);
  }
}

// ---------------- output heads ----------------

__global__ __launch_bounds__(256) void k_edge_cls(
    const float* __restrict__ h, const float* __restrict__ ef,
    const int* __restrict__ src, const int* __restrict__ dst,
    const float* __restrict__ w1, const float* __restrict__ b1,
    const float* __restrict__ w2, const float* __restrict__ b2, float* __restrict__ out) {
  __shared__ float w1l[192 * 64];
  int tid = threadIdx.x;
#pragma unroll
  for (int q = 0; q < 48; ++q) w1l[q * 256 + tid] = w1[q * 256 + tid];
  __syncthreads();
  int lane = tid & 63, w = tid >> 6;
  int ebase = blockIdx.x * 16 + w * 4;
  float fr[4][3], hid[4];
#pragma unroll
  for (int t = 0; t < 4; ++t) {
    int eid = ebase + t;
    int s = src[eid], d = dst[eid];
    fr[t][0] = h[s * 64 + lane];
    fr[t][1] = h[d * 64 + lane];
    fr[t][2] = ef[eid * 64 + lane];
    hid[t] = b1[lane];
  }
#pragma unroll
  for (int seg = 0; seg < 3; ++seg) {
#pragma unroll
    for (int kk = 0; kk < 64; ++kk) {
      float wv = w1l[(seg * 64 + kk) * 64 + lane];
#pragma unroll
      for (int t = 0; t < 4; ++t) hid[t] += bcast(fr[t][seg], kk) * wv;
    }
  }
  float w2v = w2[lane];
  float b2v = b2[0];
#pragma unroll
  for (int t = 0; t < 4; ++t) {
    float p = wave_reduce_sum(fmaxf(hid[t], 0.f) * w2v);
    if (lane == 0) out[ebase + t] = 1.f / (1.f + __expf(-(p + b2v)));
  }
}

__global__ __launch_bounds__(256) void k_offset(
    const float* __restrict__ h, const float* __restrict__ w1, const float* __restrict__ b1,
    const float* __restrict__ w2, const float* __restrict__ b2, float* __restrict__ out) {
  __shared__ float w1l[4096];
  int tid = threadIdx.x;
#pragma unroll
  for (int q = 0; q < 16; ++q) w1l[q * 256 + tid] = w1[q * 256 + tid];
  __syncthreads();
  int lane = tid & 63, g = tid >> 6;
  int n = blockIdx.x * 4 + g;
  float hr = h[n * 64 + lane];
  float hid = b1[lane];
#pragma unroll
  for (int k = 0; k < 64; ++k) hid += bcast(hr, k) * w1l[k * 64 + lane];
  hid = fmaxf(hid, 0.f);
  float p0 = wave_reduce_sum(hid * w2[lane * 2]);
  float p1 = wave_reduce_sum(hid * w2[lane * 2 + 1]);
  if (lane == 0) {
    out[N_EDGES + n * 2] = p0 + b2[0];
    out[N_EDGES + n * 2 + 1] = p1 + b2[1];
  }
}

// ---------------- launcher ----------------

extern "C" void kernel_launch(void* const* d_in, const int* in_sizes, int n_in,
                              void* d_out, int out_size, void* d_ws, size_t ws_size,
                              hipStream_t stream) {
  const float* x     = (const float*)d_in[0];
  const int*   eidx  = (const int*)d_in[1];
  const float* eattr = (const float*)d_in[2];
  const float* ne_w1 = (const float*)d_in[3];
  const float* ne_b1 = (const float*)d_in[4];
  const float* ne_w2 = (const float*)d_in[5];
  const float* ne_b2 = (const float*)d_in[6];
  const float* ee_w1 = (const float*)d_in[7];
  const float* ee_b1 = (const float*)d_in[8];
  const float* ee_w2 = (const float*)d_in[9];
  const float* ee_b2 = (const float*)d_in[10];
  const float* cv_wl = (const float*)d_in[11];
  const float* cv_bl = (const float*)d_in[12];
  const float* cv_wr = (const float*)d_in[13];
  const float* cv_br = (const float*)d_in[14];
  const float* cv_we = (const float*)d_in[15];
  const float* cv_att = (const float*)d_in[16];
  const float* cv_bias = (const float*)d_in[17];
  const float* ec_w1 = (const float*)d_in[18];
  const float* ec_b1 = (const float*)d_in[19];
  const float* ec_w2 = (const float*)d_in[20];
  const float* ec_b2 = (const float*)d_in[21];
  const float* or_w1 = (const float*)d_in[22];
  const float* or_b1 = (const float*)d_in[23];
  const float* or_w2 = (const float*)d_in[24];
  const float* or_b2 = (const float*)d_in[25];

  const int* src = eidx;
  const int* dst = eidx + N_EDGES;

  float* fws = (float*)d_ws;
  size_t o = 0;
  float* h  = fws + o; o += (size_t)N_NODES * 64;
  float* ef = fws + o; o += (size_t)EP * 64;
  float* xl = fws + o; o += (size_t)N_NODES * 256;
  float* xr = fws + o; o += (size_t)N_NODES * 256;
  float* lg = fws + o; o += (size_t)EP * 4;
  int* iws = (int*)(fws + o);
  int* row_ptr = iws;
  int* col_idx = iws + (N_NODES + 64);
  int* cnt  = col_idx + EP;
  int* fill = cnt + N_NODES;

  float* out = (float*)d_out;

  // CSR build (edge_index is fixed across the whole forward pass)
  k_zero<<<(N_NODES + 255) / 256, 256, 0, stream>>>(cnt, fill);
  k_count<<<(N_EDGES + 255) / 256, 256, 0, stream>>>(dst, cnt);
  k_scan<<<1, 1024, 0, stream>>>(cnt, row_ptr);
  k_scatter<<<(EP + 255) / 256, 256, 0, stream>>>(dst, row_ptr, fill, col_idx);
  k_sort<<<(N_NODES + 255) / 256, 256, 0, stream>>>(row_ptr, col_idx);

  // encoders
  k_node_enc<<<N_NODES / 4, 256, 0, stream>>>(x, ne_w1, ne_b1, ne_w2, ne_b2, h);
  k_edge_enc<<<N_EDGES / 4, 256, 0, stream>>>(eattr, ee_w1, ee_b1, ee_w2, ee_b2, ef);
  k_loop_feat<<<N_NODES / 4, 256, 0, stream>>>(row_ptr, col_idx, ef);

  // 3 GATv2 layers
  for (int l = 0; l < 3; ++l) {
    const float* wl = cv_wl + (size_t)l * 64 * 256;
    const float* bl = cv_bl + (size_t)l * 256;
    const float* wr = cv_wr + (size_t)l * 64 * 256;
    const float* br = cv_br + (size_t)l * 256;
    const float* wwe = cv_we + (size_t)l * 64 * 256;
    const float* at = cv_att + (size_t)l * 256;
    const float* bi = cv_bias + (size_t)l * 64;
    k_xlr<<<1250, 256, 0, stream>>>(h, wl, bl, xl);
    k_xlr<<<1250, 256, 0, stream>>>(h, wr, br, xr);
    k_edge_logits<<<EP / 16, 256, 0, stream>>>(xl, xr, ef, src, dst, wwe, at, lg);
    k_node_agg<<<N_NODES, 256, 0, stream>>>(xl, lg, row_ptr, col_idx, src, bi, h);
  }

  // heads
  k_edge_cls<<<N_EDGES / 16, 256, 0, stream>>>(h, ef, src, dst, ec_w1, ec_b1, ec_w2, ec_b2, out);
  k_offset<<<N_NODES / 4, 256, 0, stream>>>(h, or_w1, or_b1, or_w2, or_b2, out);
}

// Round 2
// 781.775 us; speedup vs baseline: 2.5533x; 2.5533x over previous
//
#include <hip/hip_runtime.h>

#define N_NODES 20000
#define N_EDGES 160000
#define EP (N_EDGES + N_NODES)   // 180000 edges incl. self loops

typedef __attribute__((ext_vector_type(8))) short bf16x8;
typedef __attribute__((ext_vector_type(4))) float f32x4;

__device__ __forceinline__ short f2bf(float f) {
  unsigned u = __float_as_uint(f);
  unsigned r = (u + 0x7FFFu + ((u >> 16) & 1u)) >> 16;  // RNE
  return (short)r;
}

__device__ __forceinline__ f32x4 mfma16(bf16x8 a, bf16x8 b, f32x4 c) {
  return __builtin_amdgcn_mfma_f32_16x16x32_bf16(a, b, c, 0, 0, 0);
}

__device__ __forceinline__ float bcast(float v, int k) {
  return __uint_as_float(__builtin_amdgcn_readlane(__float_as_uint(v), k));
}

__device__ __forceinline__ float wave_reduce_sum(float v) {
#pragma unroll
  for (int o = 32; o > 0; o >>= 1) v += __shfl_down(v, o, 64);
  return v;
}

__device__ __forceinline__ float wave_reduce_max(float v) {
#pragma unroll
  for (int o = 32; o > 0; o >>= 1) v = fmaxf(v, __shfl_down(v, o, 64));
  return v;
}

// ---------------- fp32 -> bf16 bulk convert ----------------

__global__ void k_tobf(const float* __restrict__ s, short* __restrict__ d, int n4) {
  int i = blockIdx.x * blockDim.x + threadIdx.x;
  if (i >= n4) return;
  float4 v = ((const float4*)s)[i];
  short4 o;
  o.x = f2bf(v.x); o.y = f2bf(v.y); o.z = f2bf(v.z); o.w = f2bf(v.w);
  ((short4*)d)[i] = o;
}

// ---------------- CSR build ----------------

__global__ void k_zero(int* __restrict__ cnt, int* __restrict__ fill) {
  int i = blockIdx.x * blockDim.x + threadIdx.x;
  if (i < N_NODES) { cnt[i] = 0; fill[i] = 0; }
}

__global__ void k_count(const int* __restrict__ dst, int* __restrict__ cnt) {
  int i = blockIdx.x * blockDim.x + threadIdx.x;
  if (i < N_EDGES) atomicAdd(&cnt[dst[i]], 1);
}

__global__ void k_scan(const int* __restrict__ cnt, int* __restrict__ row_ptr) {
  __shared__ int sh[1024];
  __shared__ int carry;
  int tid = threadIdx.x;
  if (tid == 0) { carry = 0; row_ptr[0] = 0; }
  __syncthreads();
  for (int base = 0; base < N_NODES; base += 1024) {
    int i = base + tid;
    int v = (i < N_NODES) ? (cnt[i] + 1) : 0;  // +1 self loop
    sh[tid] = v;
    __syncthreads();
#pragma unroll
    for (int off = 1; off < 1024; off <<= 1) {
      int t = (tid >= off) ? sh[tid - off] : 0;
      __syncthreads();
      sh[tid] += t;
      __syncthreads();
    }
    int rp = carry + sh[tid];
    if (i < N_NODES) row_ptr[i + 1] = rp;
    __syncthreads();
    if (tid == 1023) carry += sh[1023];
    __syncthreads();
  }
}

__global__ void k_scatter(const int* __restrict__ dst, const int* __restrict__ row_ptr,
                          int* __restrict__ fill, int* __restrict__ col_idx) {
  int i = blockIdx.x * blockDim.x + threadIdx.x;
  if (i >= EP) return;
  int d = (i < N_EDGES) ? dst[i] : (i - N_EDGES);
  int p = row_ptr[d] + atomicAdd(&fill[d], 1);
  col_idx[p] = i;
}

__global__ void k_sort(const int* __restrict__ row_ptr, int* __restrict__ col_idx) {
  int n = blockIdx.x * blockDim.x + threadIdx.x;
  if (n >= N_NODES) return;
  int s = row_ptr[n], e = row_ptr[n + 1];
  for (int i = s + 1; i < e; ++i) {
    int v = col_idx[i];
    int j = i - 1;
    while (j >= s && col_idx[j] > v) { col_idx[j + 1] = col_idx[j]; --j; }
    col_idx[j + 1] = v;
  }
}

// ---------------- encoders ----------------

__global__ __launch_bounds__(256) void k_node_enc(
    const float* __restrict__ x, const float* __restrict__ w1, const float* __restrict__ b1,
    const float* __restrict__ w2, const float* __restrict__ b2, float* __restrict__ h) {
  __shared__ float w2l[4096];
  int tid = threadIdx.x;
#pragma unroll
  for (int q = 0; q < 16; ++q) w2l[q * 256 + tid] = w2[q * 256 + tid];
  __syncthreads();
  int lane = tid & 63, g = tid >> 6;
  int n = blockIdx.x * 4 + g;
  float x0 = x[n * 2], x1 = x[n * 2 + 1];
  float hid = fmaxf(x0 * w1[lane] + x1 * w1[64 + lane] + b1[lane], 0.f);
  float out = b2[lane];
#pragma unroll
  for (int k = 0; k < 64; ++k) out += bcast(hid, k) * w2l[k * 64 + lane];
  h[n * 64 + lane] = out;
}

__global__ __launch_bounds__(256) void k_edge_enc(
    const float* __restrict__ ea, const float* __restrict__ w1, const float* __restrict__ b1,
    const float* __restrict__ w2, const float* __restrict__ b2, float* __restrict__ ef) {
  __shared__ float w2l[4096];
  int tid = threadIdx.x;
#pragma unroll
  for (int q = 0; q < 16; ++q) w2l[q * 256 + tid] = w2[q * 256 + tid];
  __syncthreads();
  int lane = tid & 63, g = tid >> 6;
  int i = blockIdx.x * 4 + g;
  float a0 = ea[i * 3], a1 = ea[i * 3 + 1], a2 = ea[i * 3 + 2];
  float hid = fmaxf(a0 * w1[lane] + a1 * w1[64 + lane] + a2 * w1[128 + lane] + b1[lane], 0.f);
  float out = b2[lane];
#pragma unroll
  for (int k = 0; k < 64; ++k) out += bcast(hid, k) * w2l[k * 64 + lane];
  ef[i * 64 + lane] = out;
}

// self-loop edge features: mean of incoming original-edge features (deterministic via CSR)
__global__ __launch_bounds__(256) void k_loop_feat(
    const int* __restrict__ row_ptr, const int* __restrict__ col_idx, float* __restrict__ ef) {
  int tid = threadIdx.x, lane = tid & 63, g = tid >> 6;
  int n = blockIdx.x * 4 + g;
  int s = row_ptr[n], e = row_ptr[n + 1];
  float acc = 0.f;
  for (int i = s; i < e; ++i) {
    int eid = col_idx[i];
    if (eid < N_EDGES) acc += ef[eid * 64 + lane];
  }
  int c = e - s - 1;  // original in-degree
  ef[(N_EDGES + n) * 64 + lane] = acc / (float)(c > 0 ? c : 1);
}

// ---------------- GAT layer (MFMA) ----------------

// out[n][c] = bias[c] + sum_k h[n][k] * W[k][c]   (W: [64,256]); 16 nodes/block.
// Wave w owns channels [w*64, w*64+64). B frags in registers (fp32->bf16 in-reg).
__global__ __launch_bounds__(256) void k_xlr_mfma(
    const short* __restrict__ hb, const float* __restrict__ W,
    const float* __restrict__ bias, float* __restrict__ out) {
  int tid = threadIdx.x;
  int w = tid >> 6, lane = tid & 63, q = lane & 15, g = lane >> 4;
  int cbase = w * 64;
  bf16x8 Bf[4][2];
  float bv[4];
#pragma unroll
  for (int t = 0; t < 4; ++t) {
    bv[t] = bias[cbase + t * 16 + q];
#pragma unroll
    for (int kh = 0; kh < 2; ++kh) {
      bf16x8 b;
#pragma unroll
      for (int j = 0; j < 8; ++j)
        b[j] = f2bf(W[(kh * 32 + g * 8 + j) * 256 + cbase + t * 16 + q]);
      Bf[t][kh] = b;
    }
  }
  int n0 = blockIdx.x * 16;
  const short* arow = hb + (size_t)(n0 + q) * 64;
  bf16x8 A0 = *(const bf16x8*)(arow + g * 8);
  bf16x8 A1 = *(const bf16x8*)(arow + 32 + g * 8);
#pragma unroll
  for (int t = 0; t < 4; ++t) {
    f32x4 z = {0.f, 0.f, 0.f, 0.f};
    z = mfma16(A0, Bf[t][0], z);
    z = mfma16(A1, Bf[t][1], z);
#pragma unroll
    for (int r = 0; r < 4; ++r)
      out[(size_t)(n0 + g * 4 + r) * 256 + cbase + t * 16 + q] = z[r] + bv[t];
  }
}

// per edge: ee = e_f[e]@we (MFMA) ; m = leaky(xl[src]+xr[dst]+ee) ; lg[e][h] = <m[h,:],att[h,:]>
// 16 edges/block; wave w owns head w (channels [w*64, w*64+64)).
__global__ __launch_bounds__(256) void k_elog_mfma(
    const float* __restrict__ xl, const float* __restrict__ xr,
    const short* __restrict__ efb, const int* __restrict__ src, const int* __restrict__ dst,
    const float* __restrict__ we, const float* __restrict__ att, float* __restrict__ lg) {
  int tid = threadIdx.x;
  int w = tid >> 6, lane = tid & 63, q = lane & 15, g = lane >> 4;
  int cbase = w * 64;
  bf16x8 Bf[4][2];
  float av[4];
#pragma unroll
  for (int t = 0; t < 4; ++t) {
    av[t] = att[cbase + t * 16 + q];
#pragma unroll
    for (int kh = 0; kh < 2; ++kh) {
      bf16x8 b;
#pragma unroll
      for (int j = 0; j < 8; ++j)
        b[j] = f2bf(we[(kh * 32 + g * 8 + j) * 256 + cbase + t * 16 + q]);
      Bf[t][kh] = b;
    }
  }
  int e0 = blockIdx.x * 16;
  const short* arow = efb + (size_t)(e0 + q) * 64;
  bf16x8 A0 = *(const bf16x8*)(arow + g * 8);
  bf16x8 A1 = *(const bf16x8*)(arow + 32 + g * 8);
  f32x4 acc[4];
#pragma unroll
  for (int t = 0; t < 4; ++t) {
    f32x4 z = {0.f, 0.f, 0.f, 0.f};
    z = mfma16(A0, Bf[t][0], z);
    acc[t] = mfma16(A1, Bf[t][1], z);
  }
#pragma unroll
  for (int r = 0; r < 4; ++r) {
    int e = e0 + g * 4 + r;
    int s, d;
    if (e < N_EDGES) { s = src[e]; d = dst[e]; } else { s = d = e - N_EDGES; }
    float p = 0.f;
#pragma unroll
    for (int t = 0; t < 4; ++t) {
      int c = cbase + t * 16 + q;
      float m = xl[(size_t)s * 256 + c] + xr[(size_t)d * 256 + c] + acc[t][r];
      m = m > 0.f ? m : 0.2f * m;
      p += m * av[t];
    }
    p += __shfl_xor(p, 1, 64);
    p += __shfl_xor(p, 2, 64);
    p += __shfl_xor(p, 4, 64);
    p += __shfl_xor(p, 8, 64);
    if (q == 0) lg[(size_t)e * 4 + w] = p;
  }
}

// segment softmax + aggregation + mean over heads + bias + relu + residual, per dst node
__global__ __launch_bounds__(256) void k_node_agg(
    const float* __restrict__ xl, const float* __restrict__ logits,
    const int* __restrict__ row_ptr, const int* __restrict__ col_idx,
    const int* __restrict__ src, const float* __restrict__ bias, float* __restrict__ h) {
  __shared__ float mxs[4], ssum[4], sm[256];
  int tid = threadIdx.x, lane = tid & 63, hw = tid >> 6;
  int n = blockIdx.x;
  int s0 = row_ptr[n], s1 = row_ptr[n + 1];
  float m = -3.4e38f;
  for (int i = s0 + lane; i < s1; i += 64) m = fmaxf(m, logits[col_idx[i] * 4 + hw]);
  m = wave_reduce_max(m);
  if (lane == 0) mxs[hw] = m;
  __syncthreads();
  float mx = mxs[hw];
  float sum = 0.f;
  for (int i = s0 + lane; i < s1; i += 64) sum += __expf(logits[col_idx[i] * 4 + hw] - mx);
  sum = wave_reduce_sum(sum);
  if (lane == 0) ssum[hw] = sum;
  __syncthreads();
  float inv = 1.f / ssum[hw];
  float acc = 0.f;
  for (int i = s0; i < s1; ++i) {
    int eid = col_idx[i];
    int sn = (eid < N_EDGES) ? src[eid] : n;
    float al = __expf(logits[eid * 4 + hw] - mx) * inv;
    acc += al * xl[sn * 256 + tid];
  }
  sm[tid] = acc;
  __syncthreads();
  if (tid < 64) {
    float v = 0.25f * (sm[tid] + sm[tid + 64] + sm[tid + 128] + sm[tid + 192]) + bias[tid];
    h[n * 64 + tid] += fmaxf(v, 0.f);
  }
}

// ---------------- output heads ----------------

// hid = relu([h[s],h[d],ef[e]] @ w1 + b1); out = sigmoid(hid . w2 + b2); 16 edges/block.
// Wave w owns output channels [w*16, w*16+16). K = 192 = 6 frag-steps.
__global__ __launch_bounds__(256) void k_ecls_mfma(
    const short* __restrict__ hb, const short* __restrict__ efb,
    const int* __restrict__ src, const int* __restrict__ dst,
    const float* __restrict__ w1, const float* __restrict__ b1,
    const float* __restrict__ w2, const float* __restrict__ b2, float* __restrict__ out) {
  __shared__ float sm[64];
  int tid = threadIdx.x;
  int w = tid >> 6, lane = tid & 63, q = lane & 15, g = lane >> 4;
  int c = w * 16 + q;
  bf16x8 Bf[6];
#pragma unroll
  for (int kh = 0; kh < 6; ++kh) {
    bf16x8 b;
#pragma unroll
    for (int j = 0; j < 8; ++j)
      b[j] = f2bf(w1[(size_t)(kh * 32 + g * 8 + j) * 64 + c]);
    Bf[kh] = b;
  }
  float b1v = b1[c];
  float w2v = w2[c];
  int e0 = blockIdx.x * 16;
  int eq = e0 + q;
  int sq = src[eq], dq = dst[eq];
  const short* hs = hb + (size_t)sq * 64;
  const short* hd = hb + (size_t)dq * 64;
  const short* ee = efb + (size_t)eq * 64;
  f32x4 acc = {0.f, 0.f, 0.f, 0.f};
  acc = mfma16(*(const bf16x8*)(hs + g * 8), Bf[0], acc);
  acc = mfma16(*(const bf16x8*)(hs + 32 + g * 8), Bf[1], acc);
  acc = mfma16(*(const bf16x8*)(hd + g * 8), Bf[2], acc);
  acc = mfma16(*(const bf16x8*)(hd + 32 + g * 8), Bf[3], acc);
  acc = mfma16(*(const bf16x8*)(ee + g * 8), Bf[4], acc);
  acc = mfma16(*(const bf16x8*)(ee + 32 + g * 8), Bf[5], acc);
#pragma unroll
  for (int r = 0; r < 4; ++r) {
    float hv = fmaxf(acc[r] + b1v, 0.f) * w2v;
    hv += __shfl_xor(hv, 1, 64);
    hv += __shfl_xor(hv, 2, 64);
    hv += __shfl_xor(hv, 4, 64);
    hv += __shfl_xor(hv, 8, 64);
    if (q == 0) sm[w * 16 + g * 4 + r] = hv;
  }
  __syncthreads();
  if (tid < 16) {
    float t = sm[tid] + sm[16 + tid] + sm[32 + tid] + sm[48 + tid] + b2[0];
    out[e0 + tid] = 1.f / (1.f + __expf(-t));
  }
}

__global__ __launch_bounds__(256) void k_offset(
    const float* __restrict__ h, const float* __restrict__ w1, const float* __restrict__ b1,
    const float* __restrict__ w2, const float* __restrict__ b2, float* __restrict__ out) {
  __shared__ float w1l[4096];
  int tid = threadIdx.x;
#pragma unroll
  for (int q = 0; q < 16; ++q) w1l[q * 256 + tid] = w1[q * 256 + tid];
  __syncthreads();
  int lane = tid & 63, g = tid >> 6;
  int n = blockIdx.x * 4 + g;
  float hr = h[n * 64 + lane];
  float hid = b1[lane];
#pragma unroll
  for (int k = 0; k < 64; ++k) hid += bcast(hr, k) * w1l[k * 64 + lane];
  hid = fmaxf(hid, 0.f);
  float p0 = wave_reduce_sum(hid * w2[lane * 2]);
  float p1 = wave_reduce_sum(hid * w2[lane * 2 + 1]);
  if (lane == 0) {
    out[N_EDGES + n * 2] = p0 + b2[0];
    out[N_EDGES + n * 2 + 1] = p1 + b2[1];
  }
}

// ---------------- launcher ----------------

extern "C" void kernel_launch(void* const* d_in, const int* in_sizes, int n_in,
                              void* d_out, int out_size, void* d_ws, size_t ws_size,
                              hipStream_t stream) {
  const float* x     = (const float*)d_in[0];
  const int*   eidx  = (const int*)d_in[1];
  const float* eattr = (const float*)d_in[2];
  const float* ne_w1 = (const float*)d_in[3];
  const float* ne_b1 = (const float*)d_in[4];
  const float* ne_w2 = (const float*)d_in[5];
  const float* ne_b2 = (const float*)d_in[6];
  const float* ee_w1 = (const float*)d_in[7];
  const float* ee_b1 = (const float*)d_in[8];
  const float* ee_w2 = (const float*)d_in[9];
  const float* ee_b2 = (const float*)d_in[10];
  const float* cv_wl = (const float*)d_in[11];
  const float* cv_bl = (const float*)d_in[12];
  const float* cv_wr = (const float*)d_in[13];
  const float* cv_br = (const float*)d_in[14];
  const float* cv_we = (const float*)d_in[15];
  const float* cv_att = (const float*)d_in[16];
  const float* cv_bias = (const float*)d_in[17];
  const float* ec_w1 = (const float*)d_in[18];
  const float* ec_b1 = (const float*)d_in[19];
  const float* ec_w2 = (const float*)d_in[20];
  const float* ec_b2 = (const float*)d_in[21];
  const float* or_w1 = (const float*)d_in[22];
  const float* or_b1 = (const float*)d_in[23];
  const float* or_w2 = (const float*)d_in[24];
  const float* or_b2 = (const float*)d_in[25];

  const int* src = eidx;
  const int* dst = eidx + N_EDGES;

  float* fws = (float*)d_ws;
  size_t o = 0;
  float* h  = fws + o; o += (size_t)N_NODES * 64;
  float* ef = fws + o; o += (size_t)EP * 64;
  float* xl = fws + o; o += (size_t)N_NODES * 256;
  float* xr = fws + o; o += (size_t)N_NODES * 256;
  float* lg = fws + o; o += (size_t)EP * 4;
  short* hb  = (short*)(fws + o); o += (size_t)N_NODES * 64 / 2;
  short* efb = (short*)(fws + o); o += (size_t)EP * 64 / 2;
  int* iws = (int*)(fws + o);
  int* row_ptr = iws;
  int* col_idx = iws + (N_NODES + 64);
  int* cnt  = col_idx + EP;
  int* fill = cnt + N_NODES;

  float* out = (float*)d_out;

  // CSR build
  k_zero<<<(N_NODES + 255) / 256, 256, 0, stream>>>(cnt, fill);
  k_count<<<(N_EDGES + 255) / 256, 256, 0, stream>>>(dst, cnt);
  k_scan<<<1, 1024, 0, stream>>>(cnt, row_ptr);
  k_scatter<<<(EP + 255) / 256, 256, 0, stream>>>(dst, row_ptr, fill, col_idx);
  k_sort<<<(N_NODES + 255) / 256, 256, 0, stream>>>(row_ptr, col_idx);

  // encoders
  k_node_enc<<<N_NODES / 4, 256, 0, stream>>>(x, ne_w1, ne_b1, ne_w2, ne_b2, h);
  k_edge_enc<<<N_EDGES / 4, 256, 0, stream>>>(eattr, ee_w1, ee_b1, ee_w2, ee_b2, ef);
  k_loop_feat<<<N_NODES / 4, 256, 0, stream>>>(row_ptr, col_idx, ef);

  // bf16 copies
  k_tobf<<<(EP * 64 / 4 + 255) / 256, 256, 0, stream>>>(ef, efb, EP * 64 / 4);
  k_tobf<<<(N_NODES * 64 / 4 + 255) / 256, 256, 0, stream>>>(h, hb, N_NODES * 64 / 4);

  // 3 GATv2 layers
  for (int l = 0; l < 3; ++l) {
    const float* wl = cv_wl + (size_t)l * 64 * 256;
    const float* bl = cv_bl + (size_t)l * 256;
    const float* wr = cv_wr + (size_t)l * 64 * 256;
    const float* br = cv_br + (size_t)l * 256;
    const float* wwe = cv_we + (size_t)l * 64 * 256;
    const float* at = cv_att + (size_t)l * 256;
    const float* bi = cv_bias + (size_t)l * 64;
    k_xlr_mfma<<<N_NODES / 16, 256, 0, stream>>>(hb, wl, bl, xl);
    k_xlr_mfma<<<N_NODES / 16, 256, 0, stream>>>(hb, wr, br, xr);
    k_elog_mfma<<<EP / 16, 256, 0, stream>>>(xl, xr, efb, src, dst, wwe, at, lg);
    k_node_agg<<<N_NODES, 256, 0, stream>>>(xl, lg, row_ptr, col_idx, src, bi, h);
    k_tobf<<<(N_NODES * 64 / 4 + 255) / 256, 256, 0, stream>>>(h, hb, N_NODES * 64 / 4);
  }

  // heads
  k_ecls_mfma<<<N_EDGES / 16, 256, 0, stream>>>(hb, efb, src, dst, ec_w1, ec_b1, ec_w2, ec_b2, out);
  k_offset<<<N_NODES / 4, 256, 0, stream>>>(h, or_w1, or_b1, or_w2, or_b2, out);
}

// Round 3
// 557.575 us; speedup vs baseline: 3.5800x; 1.4021x over previous
//
#include <hip/hip_runtime.h>

#define N_NODES 20000
#define N_EDGES 160000
#define EP (N_EDGES + N_NODES)   // 180000 edges incl. self loops
#define NBLK ((N_NODES + 255) / 256)  // 79
#define PREP_SEG 16384

typedef __attribute__((ext_vector_type(8))) short bf16x8;
typedef __attribute__((ext_vector_type(4))) float f32x4;

__device__ __forceinline__ short f2bf(float f) {
  unsigned u = __float_as_uint(f);
  unsigned r = (u + 0x7FFFu + ((u >> 16) & 1u)) >> 16;  // RNE
  return (short)r;
}
__device__ __forceinline__ float b2f(short s) {
  return __uint_as_float(((unsigned)(unsigned short)s) << 16);
}

__device__ __forceinline__ f32x4 mfma16(bf16x8 a, bf16x8 b, f32x4 c) {
  return __builtin_amdgcn_mfma_f32_16x16x32_bf16(a, b, c, 0, 0, 0);
}

__device__ __forceinline__ float bcast(float v, int k) {
  return __uint_as_float(__builtin_amdgcn_readlane(__float_as_uint(v), k));
}

__device__ __forceinline__ float wred_sum(float v) {
#pragma unroll
  for (int o = 32; o > 0; o >>= 1) v += __shfl_xor(v, o, 64);
  return v;
}
__device__ __forceinline__ float wred_max(float v) {
#pragma unroll
  for (int o = 32; o > 0; o >>= 1) v = fmaxf(v, __shfl_xor(v, o, 64));
  return v;
}

// ---------------- weight fragment prep (bf16, MFMA frag order) ----------------
// frag pattern (validated r1): A[row=q][k=kh*32+g*8+j]; B[col][k] same k-mapping.
__global__ void k_prep_all(const float* __restrict__ cv_wl, const float* __restrict__ cv_wr,
                           const float* __restrict__ cv_we, const float* __restrict__ ec_w1,
                           const float* __restrict__ ee_w2,
                           short* __restrict__ wlf, short* __restrict__ wrf,
                           short* __restrict__ wef, short* __restrict__ updf,
                           short* __restrict__ eclsf, short* __restrict__ encf) {
  int i = blockIdx.x * 256 + threadIdx.x;
  if (i < 12 * PREP_SEG) {
    int grp = i / PREP_SEG;
    int r = i % PREP_SEG;
    int kind = grp / 3, l = grp % 3;
    int j = r & 7, lane = (r >> 3) & 63;
    int q = lane & 15, g = lane >> 4;
    if (kind < 3) {  // wl/wr/we : [64,256], out cols c = w*64+t*16+q
      int kh = (r >> 9) & 1, t = (r >> 10) & 3, w = r >> 12;
      int k = kh * 32 + g * 8 + j, c = w * 64 + t * 16 + q;
      const float* W = (kind == 0 ? cv_wl : kind == 1 ? cv_wr : cv_we) + (size_t)l * 64 * 256;
      short* out = (kind == 0 ? wlf : kind == 1 ? wrf : wef) + (size_t)l * PREP_SEG;
      out[r] = f2bf(W[k * 256 + c]);
    } else {        // folded update: Wfold[h*64+kk][c] = 0.25*wl[kk][h*64+c], K=256, Ncol=64
      int kh = (r >> 9) & 7, w = r >> 12;
      int k = kh * 32 + g * 8 + j, c = w * 16 + q;
      const float* W = cv_wl + (size_t)l * 64 * 256;
      updf[(size_t)l * PREP_SEG + r] = f2bf(0.25f * W[(k & 63) * 256 + (k >> 6) * 64 + c]);
    }
  } else if (i < 12 * PREP_SEG + 12288) {  // ec_w1 [192,64], 6 k-frags
    int r = i - 12 * PREP_SEG;
    int j = r & 7, lane = (r >> 3) & 63, f = r >> 9;
    int w = f / 6, kh = f % 6;
    int q = lane & 15, g = lane >> 4;
    int k = kh * 32 + g * 8 + j, c = w * 16 + q;
    eclsf[r] = f2bf(ec_w1[(size_t)k * 64 + c]);
  } else {                                  // ee_w2 [64,64], 2 k-frags
    int r = i - 12 * PREP_SEG - 12288;
    if (r >= 4096) return;
    int j = r & 7, lane = (r >> 3) & 63, f = r >> 9;
    int w = f >> 1, kh = f & 1;
    int q = lane & 15, g = lane >> 4;
    int k = kh * 32 + g * 8 + j, c = w * 16 + q;
    encf[r] = f2bf(ee_w2[(size_t)k * 64 + c]);
  }
}

// ---------------- CSR build ----------------

__global__ void k_zero(int* __restrict__ cnt, int* __restrict__ fill) {
  int i = blockIdx.x * blockDim.x + threadIdx.x;
  if (i < N_NODES) { cnt[i] = 0; fill[i] = 0; }
}

__global__ void k_count(const int* __restrict__ dst, int* __restrict__ cnt) {
  int i = blockIdx.x * blockDim.x + threadIdx.x;
  if (i < N_EDGES) atomicAdd(&cnt[dst[i]], 1);
}

__global__ void k_scan1(const int* __restrict__ cnt, int* __restrict__ row_ptr,
                        int* __restrict__ bsum) {
  __shared__ int sh[256];
  int t = threadIdx.x, b = blockIdx.x, i = b * 256 + t;
  int v = (i < N_NODES) ? cnt[i] + 1 : 0;  // +1 self loop
  sh[t] = v;
  __syncthreads();
#pragma unroll
  for (int off = 1; off < 256; off <<= 1) {
    int x = (t >= off) ? sh[t - off] : 0;
    __syncthreads();
    sh[t] += x;
    __syncthreads();
  }
  if (i < N_NODES) row_ptr[i + 1] = sh[t];
  if (t == 255) bsum[b] = sh[255];
}

__global__ void k_scan2(const int* __restrict__ bsum, int* __restrict__ boff) {
  __shared__ int sh[256];
  int t = threadIdx.x;
  int v = (t < NBLK) ? bsum[t] : 0;
  sh[t] = v;
  __syncthreads();
#pragma unroll
  for (int off = 1; off < 256; off <<= 1) {
    int x = (t >= off) ? sh[t - off] : 0;
    __syncthreads();
    sh[t] += x;
    __syncthreads();
  }
  if (t < NBLK) boff[t] = sh[t] - v;  // exclusive
}

__global__ void k_scan3(const int* __restrict__ boff, int* __restrict__ row_ptr) {
  int t = threadIdx.x, b = blockIdx.x, i = b * 256 + t;
  if (i < N_NODES) row_ptr[i + 1] += boff[b];
  if (i == 0) row_ptr[0] = 0;
}

__global__ void k_scatter(const int* __restrict__ dst, const int* __restrict__ row_ptr,
                          int* __restrict__ fill, int* __restrict__ col_idx,
                          int* __restrict__ pdst) {
  int i = blockIdx.x * blockDim.x + threadIdx.x;
  if (i >= EP) return;
  int d = (i < N_EDGES) ? dst[i] : (i - N_EDGES);
  int p = row_ptr[d] + atomicAdd(&fill[d], 1);
  col_idx[p] = i;
  pdst[p] = d;
}

__global__ void k_sort(const int* __restrict__ row_ptr, int* __restrict__ col_idx) {
  int n = blockIdx.x * blockDim.x + threadIdx.x;
  if (n >= N_NODES) return;
  int s = row_ptr[n], e = row_ptr[n + 1];
  for (int i = s + 1; i < e; ++i) {
    int v = col_idx[i];
    int j = i - 1;
    while (j >= s && col_idx[j] > v) { col_idx[j + 1] = col_idx[j]; --j; }
    col_idx[j + 1] = v;
  }
}

// ---------------- encoders ----------------

__global__ __launch_bounds__(256) void k_node_enc(
    const float* __restrict__ x, const float* __restrict__ w1, const float* __restrict__ b1,
    const float* __restrict__ w2, const float* __restrict__ b2,
    float* __restrict__ h, short* __restrict__ hb) {
  __shared__ float w2l[4096];
  int tid = threadIdx.x;
#pragma unroll
  for (int q = 0; q < 16; ++q) w2l[q * 256 + tid] = w2[q * 256 + tid];
  __syncthreads();
  int lane = tid & 63, g = tid >> 6;
  int n = blockIdx.x * 4 + g;
  float x0 = x[n * 2], x1 = x[n * 2 + 1];
  float hid = fmaxf(x0 * w1[lane] + x1 * w1[64 + lane] + b1[lane], 0.f);
  float out = b2[lane];
#pragma unroll
  for (int k = 0; k < 64; ++k) out += bcast(hid, k) * w2l[k * 64 + lane];
  h[n * 64 + lane] = out;
  hb[n * 64 + lane] = f2bf(out);
}

// 16 edges/block: layer1 on VALU -> LDS bf16, layer2 via MFMA. Writes efb bf16.
__global__ __launch_bounds__(256) void k_edge_enc(
    const float* __restrict__ ea, const float* __restrict__ w1, const float* __restrict__ b1,
    const short* __restrict__ encf, const float* __restrict__ b2, short* __restrict__ efb) {
  __shared__ short hs[16 * 72];  // pad 8 shorts to break bank aliasing
  int tid = threadIdx.x;
  int w = tid >> 6, lane = tid & 63, q = lane & 15, g = lane >> 4;
  int e0 = blockIdx.x * 16;
#pragma unroll
  for (int t = 0; t < 4; ++t) {
    int e = e0 + w * 4 + t;
    float a0 = ea[e * 3], a1 = ea[e * 3 + 1], a2 = ea[e * 3 + 2];
    float hid = fmaxf(a0 * w1[lane] + a1 * w1[64 + lane] + a2 * w1[128 + lane] + b1[lane], 0.f);
    hs[(w * 4 + t) * 72 + lane] = f2bf(hid);
  }
  __syncthreads();
  bf16x8 A0 = *(const bf16x8*)&hs[q * 72 + g * 8];
  bf16x8 A1 = *(const bf16x8*)&hs[q * 72 + 32 + g * 8];
  bf16x8 B0 = *(const bf16x8*)(encf + ((size_t)(w * 2 + 0) * 64 + lane) * 8);
  bf16x8 B1 = *(const bf16x8*)(encf + ((size_t)(w * 2 + 1) * 64 + lane) * 8);
  f32x4 z = {0.f, 0.f, 0.f, 0.f};
  z = mfma16(A0, B0, z);
  z = mfma16(A1, B1, z);
  int c = w * 16 + q;
  float bv = b2[c];
#pragma unroll
  for (int r = 0; r < 4; ++r) efb[(size_t)(e0 + g * 4 + r) * 64 + c] = f2bf(z[r] + bv);
}

// self-loop edge feats: mean of incoming original-edge feats (deterministic via CSR)
__global__ __launch_bounds__(256) void k_loop_feat(
    const int* __restrict__ row_ptr, const int* __restrict__ col_idx, short* __restrict__ efb) {
  int tid = threadIdx.x, lane = tid & 63, g = tid >> 6;
  int n = blockIdx.x * 4 + g;
  int s = row_ptr[n], e = row_ptr[n + 1];
  float acc = 0.f;
  for (int i = s; i < e; ++i) {
    int eid = col_idx[i];
    if (eid < N_EDGES) acc += b2f(efb[(size_t)eid * 64 + lane]);
  }
  int c = e - s - 1;
  efb[(size_t)(N_EDGES + n) * 64 + lane] = f2bf(acc / (float)(c > 0 ? c : 1));
}

// ---------------- GAT layer ----------------

// xb[n][c] = bf16(bias[c] + sum_k h[n][k]*W[k][c]); 16 nodes/block, wave w -> cols [w*64,w*64+64)
__global__ __launch_bounds__(256) void k_xlr(
    const short* __restrict__ hb, const short* __restrict__ wf,
    const float* __restrict__ bias, short* __restrict__ xb) {
  int tid = threadIdx.x;
  int w = tid >> 6, lane = tid & 63, q = lane & 15, g = lane >> 4;
  int cbase = w * 64;
  int n0 = blockIdx.x * 16;
  const short* arow = hb + (size_t)(n0 + q) * 64;
  bf16x8 A0 = *(const bf16x8*)(arow + g * 8);
  bf16x8 A1 = *(const bf16x8*)(arow + 32 + g * 8);
#pragma unroll
  for (int t = 0; t < 4; ++t) {
    bf16x8 B0 = *(const bf16x8*)(wf + ((size_t)((w * 4 + t) * 2 + 0) * 64 + lane) * 8);
    bf16x8 B1 = *(const bf16x8*)(wf + ((size_t)((w * 4 + t) * 2 + 1) * 64 + lane) * 8);
    f32x4 z = {0.f, 0.f, 0.f, 0.f};
    z = mfma16(A0, B0, z);
    z = mfma16(A1, B1, z);
    float bv = bias[cbase + t * 16 + q];
#pragma unroll
    for (int r = 0; r < 4; ++r)
      xb[(size_t)(n0 + g * 4 + r) * 256 + cbase + t * 16 + q] = f2bf(z[r] + bv);
  }
}

// edges in CSR order: ee = efb[eid]@we (MFMA); m = leaky(xl[s]+xr[n]+ee); lg[h][p] = <m_h, att_h>
__global__ __launch_bounds__(256) void k_elog(
    const short* __restrict__ xlb, const short* __restrict__ xrb,
    const short* __restrict__ efb, const int* __restrict__ col_idx,
    const int* __restrict__ pdst, const int* __restrict__ src,
    const short* __restrict__ wef, const float* __restrict__ att, float* __restrict__ lg) {
  int tid = threadIdx.x;
  int w = tid >> 6, lane = tid & 63, q = lane & 15, g = lane >> 4;
  int cbase = w * 64;
  int p0 = blockIdx.x * 16;
  int eq = col_idx[p0 + q];
  const short* arow = efb + (size_t)eq * 64;
  bf16x8 A0 = *(const bf16x8*)(arow + g * 8);
  bf16x8 A1 = *(const bf16x8*)(arow + 32 + g * 8);
  f32x4 acc[4];
  float av[4];
#pragma unroll
  for (int t = 0; t < 4; ++t) {
    av[t] = att[cbase + t * 16 + q];
    bf16x8 B0 = *(const bf16x8*)(wef + ((size_t)((w * 4 + t) * 2 + 0) * 64 + lane) * 8);
    bf16x8 B1 = *(const bf16x8*)(wef + ((size_t)((w * 4 + t) * 2 + 1) * 64 + lane) * 8);
    f32x4 z = {0.f, 0.f, 0.f, 0.f};
    z = mfma16(A0, B0, z);
    acc[t] = mfma16(A1, B1, z);
  }
#pragma unroll
  for (int r = 0; r < 4; ++r) {
    int p = p0 + g * 4 + r;
    int eid = col_idx[p];
    int n = pdst[p];
    int s = (eid < N_EDGES) ? src[eid] : n;
    float pd = 0.f;
#pragma unroll
    for (int t = 0; t < 4; ++t) {
      int c = cbase + t * 16 + q;
      float m = b2f(xlb[(size_t)s * 256 + c]) + b2f(xrb[(size_t)n * 256 + c]) + acc[t][r];
      m = m > 0.f ? m : 0.2f * m;
      pd += m * av[t];
    }
    pd += __shfl_xor(pd, 1, 64);
    pd += __shfl_xor(pd, 2, 64);
    pd += __shfl_xor(pd, 4, 64);
    pd += __shfl_xor(pd, 8, 64);
    if (q == 0) lg[(size_t)w * EP + p] = pd;
  }
}

// per dst node: softmax over lg + aggregate hb[src] (64-dim) per head -> aggb[n][h*64+k] bf16
__global__ __launch_bounds__(256) void k_agg(
    const short* __restrict__ hb, const float* __restrict__ lg,
    const int* __restrict__ row_ptr, const int* __restrict__ col_idx,
    const int* __restrict__ src, short* __restrict__ aggb) {
  int tid = threadIdx.x, lane = tid & 63, hw = tid >> 6;
  int n = blockIdx.x;
  int s0 = row_ptr[n], s1 = row_ptr[n + 1];
  const float* lgh = lg + (size_t)hw * EP;
  float m = -3.4e38f;
  for (int i = s0 + lane; i < s1; i += 64) m = fmaxf(m, lgh[i]);
  m = wred_max(m);
  float sum = 0.f;
  for (int i = s0 + lane; i < s1; i += 64) sum += __expf(lgh[i] - m);
  sum = wred_sum(sum);
  float inv = 1.f / sum;
  float acc = 0.f;
  for (int p = s0; p < s1; ++p) {
    int eid = col_idx[p];
    int sp = (eid < N_EDGES) ? src[eid] : n;
    float al = __expf(lgh[p] - m) * inv;
    acc += al * b2f(hb[(size_t)sp * 64 + lane]);
  }
  aggb[(size_t)n * 256 + hw * 64 + lane] = f2bf(acc);
}

// h += relu(aggb @ Wfold + bfold); hb = bf16(h). 16 nodes/block, wave w -> cols w*16..+16
__global__ __launch_bounds__(256) void k_upd(
    const short* __restrict__ aggb, const short* __restrict__ updf,
    const float* __restrict__ bl, const float* __restrict__ bias,
    float* __restrict__ h, short* __restrict__ hb) {
  int tid = threadIdx.x;
  int w = tid >> 6, lane = tid & 63, q = lane & 15, g = lane >> 4;
  int n0 = blockIdx.x * 16;
  const short* arow = aggb + (size_t)(n0 + q) * 256;
  f32x4 z = {0.f, 0.f, 0.f, 0.f};
#pragma unroll
  for (int kh = 0; kh < 8; ++kh) {
    bf16x8 A = *(const bf16x8*)(arow + kh * 32 + g * 8);
    bf16x8 B = *(const bf16x8*)(updf + ((size_t)(w * 8 + kh) * 64 + lane) * 8);
    z = mfma16(A, B, z);
  }
  int c = w * 16 + q;
  float bf = 0.25f * (bl[c] + bl[64 + c] + bl[128 + c] + bl[192 + c]) + bias[c];
#pragma unroll
  for (int r = 0; r < 4; ++r) {
    int n = n0 + g * 4 + r;
    float nh = h[(size_t)n * 64 + c] + fmaxf(z[r] + bf, 0.f);
    h[(size_t)n * 64 + c] = nh;
    hb[(size_t)n * 64 + c] = f2bf(nh);
  }
}

// ---------------- output heads ----------------

__global__ __launch_bounds__(256) void k_ecls(
    const short* __restrict__ hb, const short* __restrict__ efb,
    const int* __restrict__ src, const int* __restrict__ dst,
    const short* __restrict__ eclsf, const float* __restrict__ b1,
    const float* __restrict__ w2, const float* __restrict__ b2, float* __restrict__ out) {
  __shared__ float sm[64];
  int tid = threadIdx.x;
  int w = tid >> 6, lane = tid & 63, q = lane & 15, g = lane >> 4;
  int c = w * 16 + q;
  float b1v = b1[c];
  float w2v = w2[c];
  int e0 = blockIdx.x * 16;
  int eq = e0 + q;
  int sq = src[eq], dq = dst[eq];
  const short* hs = hb + (size_t)sq * 64;
  const short* hd = hb + (size_t)dq * 64;
  const short* ee = efb + (size_t)eq * 64;
  f32x4 acc = {0.f, 0.f, 0.f, 0.f};
  acc = mfma16(*(const bf16x8*)(hs + g * 8),      *(const bf16x8*)(eclsf + ((size_t)(w * 6 + 0) * 64 + lane) * 8), acc);
  acc = mfma16(*(const bf16x8*)(hs + 32 + g * 8), *(const bf16x8*)(eclsf + ((size_t)(w * 6 + 1) * 64 + lane) * 8), acc);
  acc = mfma16(*(const bf16x8*)(hd + g * 8),      *(const bf16x8*)(eclsf + ((size_t)(w * 6 + 2) * 64 + lane) * 8), acc);
  acc = mfma16(*(const bf16x8*)(hd + 32 + g * 8), *(const bf16x8*)(eclsf + ((size_t)(w * 6 + 3) * 64 + lane) * 8), acc);
  acc = mfma16(*(const bf16x8*)(ee + g * 8),      *(const bf16x8*)(eclsf + ((size_t)(w * 6 + 4) * 64 + lane) * 8), acc);
  acc = mfma16(*(const bf16x8*)(ee + 32 + g * 8), *(const bf16x8*)(eclsf + ((size_t)(w * 6 + 5) * 64 + lane) * 8), acc);
#pragma unroll
  for (int r = 0; r < 4; ++r) {
    float hv = fmaxf(acc[r] + b1v, 0.f) * w2v;
    hv += __shfl_xor(hv, 1, 64);
    hv += __shfl_xor(hv, 2, 64);
    hv += __shfl_xor(hv, 4, 64);
    hv += __shfl_xor(hv, 8, 64);
    if (q == 0) sm[w * 16 + g * 4 + r] = hv;
  }
  __syncthreads();
  if (tid < 16) {
    float t = sm[tid] + sm[16 + tid] + sm[32 + tid] + sm[48 + tid] + b2[0];
    out[e0 + tid] = 1.f / (1.f + __expf(-t));
  }
}

__global__ __launch_bounds__(256) void k_offset(
    const float* __restrict__ h, const float* __restrict__ w1, const float* __restrict__ b1,
    const float* __restrict__ w2, const float* __restrict__ b2, float* __restrict__ out) {
  __shared__ float w1l[4096];
  int tid = threadIdx.x;
#pragma unroll
  for (int q = 0; q < 16; ++q) w1l[q * 256 + tid] = w1[q * 256 + tid];
  __syncthreads();
  int lane = tid & 63, g = tid >> 6;
  int n = blockIdx.x * 4 + g;
  float hr = h[n * 64 + lane];
  float hid = b1[lane];
#pragma unroll
  for (int k = 0; k < 64; ++k) hid += bcast(hr, k) * w1l[k * 64 + lane];
  hid = fmaxf(hid, 0.f);
  float p0 = wred_sum(hid * w2[lane * 2]);
  float p1 = wred_sum(hid * w2[lane * 2 + 1]);
  if (lane == 0) {
    out[N_EDGES + n * 2] = p0 + b2[0];
    out[N_EDGES + n * 2 + 1] = p1 + b2[1];
  }
}

// ---------------- launcher ----------------

extern "C" void kernel_launch(void* const* d_in, const int* in_sizes, int n_in,
                              void* d_out, int out_size, void* d_ws, size_t ws_size,
                              hipStream_t stream) {
  const float* x     = (const float*)d_in[0];
  const int*   eidx  = (const int*)d_in[1];
  const float* eattr = (const float*)d_in[2];
  const float* ne_w1 = (const float*)d_in[3];
  const float* ne_b1 = (const float*)d_in[4];
  const float* ne_w2 = (const float*)d_in[5];
  const float* ne_b2 = (const float*)d_in[6];
  const float* ee_w1 = (const float*)d_in[7];
  const float* ee_b1 = (const float*)d_in[8];
  const float* ee_w2 = (const float*)d_in[9];
  const float* ee_b2 = (const float*)d_in[10];
  const float* cv_wl = (const float*)d_in[11];
  const float* cv_bl = (const float*)d_in[12];
  const float* cv_wr = (const float*)d_in[13];
  const float* cv_br = (const float*)d_in[14];
  const float* cv_we = (const float*)d_in[15];
  const float* cv_att = (const float*)d_in[16];
  const float* cv_bias = (const float*)d_in[17];
  const float* ec_w1 = (const float*)d_in[18];
  const float* ec_b1 = (const float*)d_in[19];
  const float* ec_w2 = (const float*)d_in[20];
  const float* ec_b2 = (const float*)d_in[21];
  const float* or_w1 = (const float*)d_in[22];
  const float* or_b1 = (const float*)d_in[23];
  const float* or_w2 = (const float*)d_in[24];
  const float* or_b2 = (const float*)d_in[25];

  const int* src = eidx;
  const int* dst = eidx + N_EDGES;

  // workspace layout
  float* fws = (float*)d_ws;
  size_t o = 0;
  float* h  = fws + o; o += (size_t)N_NODES * 64;
  float* lg = fws + o; o += (size_t)EP * 4;
  short* sws = (short*)(fws + o);
  size_t so = 0;
  short* hb   = sws + so; so += (size_t)N_NODES * 64;
  short* xlb  = sws + so; so += (size_t)N_NODES * 256;
  short* xrb  = sws + so; so += (size_t)N_NODES * 256;
  short* aggb = sws + so; so += (size_t)N_NODES * 256;
  short* efb  = sws + so; so += (size_t)EP * 64;
  short* wlf  = sws + so; so += 3 * PREP_SEG;
  short* wrf  = sws + so; so += 3 * PREP_SEG;
  short* wef  = sws + so; so += 3 * PREP_SEG;
  short* updf = sws + so; so += 3 * PREP_SEG;
  short* eclsf = sws + so; so += 12288;
  short* encf  = sws + so; so += 4096;
  int* iws = (int*)(sws + so + (so & 1));
  int* row_ptr = iws;
  int* col_idx = iws + (N_NODES + 64);
  int* pdst = col_idx + EP;
  int* cnt  = pdst + EP;
  int* fill = cnt + N_NODES;
  int* bsum = fill + N_NODES;
  int* boff = bsum + 128;

  float* out = (float*)d_out;

  // weight fragment prep (all layers + heads + encoder)
  k_prep_all<<<(12 * PREP_SEG + 12288 + 4096 + 255) / 256, 256, 0, stream>>>(
      cv_wl, cv_wr, cv_we, ec_w1, ee_w2, wlf, wrf, wef, updf, eclsf, encf);

  // CSR build
  k_zero<<<(N_NODES + 255) / 256, 256, 0, stream>>>(cnt, fill);
  k_count<<<(N_EDGES + 255) / 256, 256, 0, stream>>>(dst, cnt);
  k_scan1<<<NBLK, 256, 0, stream>>>(cnt, row_ptr, bsum);
  k_scan2<<<1, 256, 0, stream>>>(bsum, boff);
  k_scan3<<<NBLK, 256, 0, stream>>>(boff, row_ptr);
  k_scatter<<<(EP + 255) / 256, 256, 0, stream>>>(dst, row_ptr, fill, col_idx, pdst);
  k_sort<<<(N_NODES + 255) / 256, 256, 0, stream>>>(row_ptr, col_idx);

  // encoders
  k_node_enc<<<N_NODES / 4, 256, 0, stream>>>(x, ne_w1, ne_b1, ne_w2, ne_b2, h, hb);
  k_edge_enc<<<N_EDGES / 16, 256, 0, stream>>>(eattr, ee_w1, ee_b1, encf, ee_b2, efb);
  k_loop_feat<<<N_NODES / 4, 256, 0, stream>>>(row_ptr, col_idx, efb);

  // 3 GATv2 layers
  for (int l = 0; l < 3; ++l) {
    const float* bl = cv_bl + (size_t)l * 256;
    const float* br = cv_br + (size_t)l * 256;
    const float* at = cv_att + (size_t)l * 256;
    const float* bi = cv_bias + (size_t)l * 64;
    k_xlr<<<N_NODES / 16, 256, 0, stream>>>(hb, wlf + (size_t)l * PREP_SEG, bl, xlb);
    k_xlr<<<N_NODES / 16, 256, 0, stream>>>(hb, wrf + (size_t)l * PREP_SEG, br, xrb);
    k_elog<<<EP / 16, 256, 0, stream>>>(xlb, xrb, efb, col_idx, pdst, src,
                                        wef + (size_t)l * PREP_SEG, at, lg);
    k_agg<<<N_NODES, 256, 0, stream>>>(hb, lg, row_ptr, col_idx, src, aggb);
    k_upd<<<N_NODES / 16, 256, 0, stream>>>(aggb, updf + (size_t)l * PREP_SEG, bl, bi, h, hb);
  }

  // heads
  k_ecls<<<N_EDGES / 16, 256, 0, stream>>>(hb, efb, src, dst, eclsf, ec_b1, ec_w2, ec_b2, out);
  k_offset<<<N_NODES / 4, 256, 0, stream>>>(h, or_w1, or_b1, or_w2, or_b2, out);
}

// Round 4
// 440.811 us; speedup vs baseline: 4.5282x; 1.2649x over previous
//
#include <hip/hip_runtime.h>

#define N_NODES 20000
#define N_EDGES 160000
#define EP (N_EDGES + N_NODES)   // 180000 edges incl. self loops
#define NBLK ((N_NODES + 255) / 256)  // 79
#define PREP_SEG 16384

typedef __attribute__((ext_vector_type(8))) short bf16x8;
typedef __attribute__((ext_vector_type(4))) float f32x4;

__device__ __forceinline__ short f2bf(float f) {
  unsigned u = __float_as_uint(f);
  unsigned r = (u + 0x7FFFu + ((u >> 16) & 1u)) >> 16;  // RNE
  return (short)r;
}
__device__ __forceinline__ float b2f(short s) {
  return __uint_as_float(((unsigned)(unsigned short)s) << 16);
}

__device__ __forceinline__ f32x4 mfma16(bf16x8 a, bf16x8 b, f32x4 c) {
  return __builtin_amdgcn_mfma_f32_16x16x32_bf16(a, b, c, 0, 0, 0);
}

__device__ __forceinline__ float bcast(float v, int k) {
  return __uint_as_float(__builtin_amdgcn_readlane(__float_as_uint(v), k));
}

__device__ __forceinline__ float wred_sum(float v) {
#pragma unroll
  for (int o = 32; o > 0; o >>= 1) v += __shfl_xor(v, o, 64);
  return v;
}
__device__ __forceinline__ float wred_max(float v) {
#pragma unroll
  for (int o = 32; o > 0; o >>= 1) v = fmaxf(v, __shfl_xor(v, o, 64));
  return v;
}

// ---------------- weight fragment prep (bf16, MFMA frag order) ----------------
__global__ void k_prep_all(const float* __restrict__ cv_wl, const float* __restrict__ cv_wr,
                           const float* __restrict__ cv_we, const float* __restrict__ ec_w1,
                           const float* __restrict__ ee_w2,
                           short* __restrict__ wlf, short* __restrict__ wrf,
                           short* __restrict__ wef, short* __restrict__ updf,
                           short* __restrict__ eclsf, short* __restrict__ encf) {
  int i = blockIdx.x * 256 + threadIdx.x;
  if (i < 12 * PREP_SEG) {
    int grp = i / PREP_SEG;
    int r = i % PREP_SEG;
    int kind = grp / 3, l = grp % 3;
    int j = r & 7, lane = (r >> 3) & 63;
    int q = lane & 15, g = lane >> 4;
    if (kind < 3) {  // wl/wr/we : [64,256], out cols c = w*64+t*16+q
      int kh = (r >> 9) & 1, t = (r >> 10) & 3, w = r >> 12;
      int k = kh * 32 + g * 8 + j, c = w * 64 + t * 16 + q;
      const float* W = (kind == 0 ? cv_wl : kind == 1 ? cv_wr : cv_we) + (size_t)l * 64 * 256;
      short* out = (kind == 0 ? wlf : kind == 1 ? wrf : wef) + (size_t)l * PREP_SEG;
      out[r] = f2bf(W[k * 256 + c]);
    } else {        // folded update: Wfold[h*64+kk][c] = 0.25*wl[kk][h*64+c], K=256, Ncol=64
      int kh = (r >> 9) & 7, w = r >> 12;
      int k = kh * 32 + g * 8 + j, c = w * 16 + q;
      const float* W = cv_wl + (size_t)l * 64 * 256;
      updf[(size_t)l * PREP_SEG + r] = f2bf(0.25f * W[(k & 63) * 256 + (k >> 6) * 64 + c]);
    }
  } else if (i < 12 * PREP_SEG + 12288) {  // ec_w1 [192,64], 6 k-frags
    int r = i - 12 * PREP_SEG;
    int j = r & 7, lane = (r >> 3) & 63, f = r >> 9;
    int w = f / 6, kh = f % 6;
    int q = lane & 15, g = lane >> 4;
    int k = kh * 32 + g * 8 + j, c = w * 16 + q;
    eclsf[r] = f2bf(ec_w1[(size_t)k * 64 + c]);
  } else {                                  // ee_w2 [64,64], 2 k-frags
    int r = i - 12 * PREP_SEG - 12288;
    if (r >= 4096) return;
    int j = r & 7, lane = (r >> 3) & 63, f = r >> 9;
    int w = f >> 1, kh = f & 1;
    int q = lane & 15, g = lane >> 4;
    int k = kh * 32 + g * 8 + j, c = w * 16 + q;
    encf[r] = f2bf(ee_w2[(size_t)k * 64 + c]);
  }
}

// ---------------- CSR build ----------------

__global__ void k_zero(int* __restrict__ cnt, int* __restrict__ fill) {
  int i = blockIdx.x * blockDim.x + threadIdx.x;
  if (i < N_NODES) { cnt[i] = 0; fill[i] = 0; }
}

__global__ void k_count(const int* __restrict__ dst, int* __restrict__ cnt) {
  int i = blockIdx.x * blockDim.x + threadIdx.x;
  if (i < N_EDGES) atomicAdd(&cnt[dst[i]], 1);
}

__global__ void k_scan1(const int* __restrict__ cnt, int* __restrict__ row_ptr,
                        int* __restrict__ bsum) {
  __shared__ int sh[256];
  int t = threadIdx.x, b = blockIdx.x, i = b * 256 + t;
  int v = (i < N_NODES) ? cnt[i] + 1 : 0;  // +1 self loop
  sh[t] = v;
  __syncthreads();
#pragma unroll
  for (int off = 1; off < 256; off <<= 1) {
    int x = (t >= off) ? sh[t - off] : 0;
    __syncthreads();
    sh[t] += x;
    __syncthreads();
  }
  if (i < N_NODES) row_ptr[i + 1] = sh[t];
  if (t == 255) bsum[b] = sh[255];
}

__global__ void k_scan2(const int* __restrict__ bsum, int* __restrict__ boff) {
  __shared__ int sh[256];
  int t = threadIdx.x;
  int v = (t < NBLK) ? bsum[t] : 0;
  sh[t] = v;
  __syncthreads();
#pragma unroll
  for (int off = 1; off < 256; off <<= 1) {
    int x = (t >= off) ? sh[t - off] : 0;
    __syncthreads();
    sh[t] += x;
    __syncthreads();
  }
  if (t < NBLK) boff[t] = sh[t] - v;  // exclusive
}

__global__ void k_scan3(const int* __restrict__ boff, int* __restrict__ row_ptr) {
  int t = threadIdx.x, b = blockIdx.x, i = b * 256 + t;
  if (i < N_NODES) row_ptr[i + 1] += boff[b];
  if (i == 0) row_ptr[0] = 0;
}

__global__ void k_scatter(const int* __restrict__ dst, const int* __restrict__ row_ptr,
                          int* __restrict__ fill, int* __restrict__ col_idx,
                          int* __restrict__ pdst) {
  int i = blockIdx.x * blockDim.x + threadIdx.x;
  if (i >= EP) return;
  int d = (i < N_EDGES) ? dst[i] : (i - N_EDGES);
  int p = row_ptr[d] + atomicAdd(&fill[d], 1);
  col_idx[p] = i;
  pdst[p] = d;
}

__global__ void k_sort(const int* __restrict__ row_ptr, int* __restrict__ col_idx) {
  int n = blockIdx.x * blockDim.x + threadIdx.x;
  if (n >= N_NODES) return;
  int s = row_ptr[n], e = row_ptr[n + 1];
  for (int i = s + 1; i < e; ++i) {
    int v = col_idx[i];
    int j = i - 1;
    while (j >= s && col_idx[j] > v) { col_idx[j + 1] = col_idx[j]; --j; }
    col_idx[j + 1] = v;
  }
}

// after sort: psrc[p] = source node of CSR slot p; pos[eid] = CSR slot of edge eid
__global__ void k_psrc(const int* __restrict__ col_idx, const int* __restrict__ pdst,
                       const int* __restrict__ src, int* __restrict__ psrc,
                       int* __restrict__ pos) {
  int p = blockIdx.x * 256 + threadIdx.x;
  if (p >= EP) return;
  int eid = col_idx[p];
  pos[eid] = p;
  psrc[p] = (eid < N_EDGES) ? src[eid] : (eid - N_EDGES);
}

// ---------------- encoders ----------------

__global__ __launch_bounds__(256) void k_node_enc(
    const float* __restrict__ x, const float* __restrict__ w1, const float* __restrict__ b1,
    const float* __restrict__ w2, const float* __restrict__ b2,
    float* __restrict__ h, short* __restrict__ hb) {
  __shared__ float w2l[4096];
  int tid = threadIdx.x;
#pragma unroll
  for (int q = 0; q < 16; ++q) w2l[q * 256 + tid] = w2[q * 256 + tid];
  __syncthreads();
  int lane = tid & 63, g = tid >> 6;
  int n = blockIdx.x * 4 + g;
  float x0 = x[n * 2], x1 = x[n * 2 + 1];
  float hid = fmaxf(x0 * w1[lane] + x1 * w1[64 + lane] + b1[lane], 0.f);
  float out = b2[lane];
#pragma unroll
  for (int k = 0; k < 64; ++k) out += bcast(hid, k) * w2l[k * 64 + lane];
  h[n * 64 + lane] = out;
  hb[n * 64 + lane] = f2bf(out);
}

// 16 edges/block: layer1 on VALU -> LDS bf16, layer2 via MFMA. Writes efc (CSR order via pos).
__global__ __launch_bounds__(256) void k_edge_enc(
    const float* __restrict__ ea, const float* __restrict__ w1, const float* __restrict__ b1,
    const short* __restrict__ encf, const float* __restrict__ b2,
    const int* __restrict__ pos, short* __restrict__ efc) {
  __shared__ short hs[16 * 72];
  int tid = threadIdx.x;
  int w = tid >> 6, lane = tid & 63, q = lane & 15, g = lane >> 4;
  int e0 = blockIdx.x * 16;
#pragma unroll
  for (int t = 0; t < 4; ++t) {
    int e = e0 + w * 4 + t;
    float a0 = ea[e * 3], a1 = ea[e * 3 + 1], a2 = ea[e * 3 + 2];
    float hid = fmaxf(a0 * w1[lane] + a1 * w1[64 + lane] + a2 * w1[128 + lane] + b1[lane], 0.f);
    hs[(w * 4 + t) * 72 + lane] = f2bf(hid);
  }
  __syncthreads();
  bf16x8 A0 = *(const bf16x8*)&hs[q * 72 + g * 8];
  bf16x8 A1 = *(const bf16x8*)&hs[q * 72 + 32 + g * 8];
  bf16x8 B0 = *(const bf16x8*)(encf + ((size_t)(w * 2 + 0) * 64 + lane) * 8);
  bf16x8 B1 = *(const bf16x8*)(encf + ((size_t)(w * 2 + 1) * 64 + lane) * 8);
  f32x4 z = {0.f, 0.f, 0.f, 0.f};
  z = mfma16(A0, B0, z);
  z = mfma16(A1, B1, z);
  int c = w * 16 + q;
  float bv = b2[c];
#pragma unroll
  for (int r = 0; r < 4; ++r) {
    int e = e0 + g * 4 + r;
    efc[(size_t)pos[e] * 64 + c] = f2bf(z[r] + bv);
  }
}

// self-loop row (last CSR slot per node) = mean of the node's original-edge rows
__global__ __launch_bounds__(256) void k_loop_feat(
    const int* __restrict__ row_ptr, short* __restrict__ efc) {
  int tid = threadIdx.x, lane = tid & 63, g = tid >> 6;
  int n = blockIdx.x * 4 + g;
  int s = row_ptr[n], e1 = row_ptr[n + 1];
  float acc = 0.f;
  for (int i = s; i < e1 - 1; ++i) acc += b2f(efc[(size_t)i * 64 + lane]);
  int c = e1 - 1 - s;
  efc[(size_t)(e1 - 1) * 64 + lane] = f2bf(acc / (float)(c > 0 ? c : 1));
}

// ---------------- GAT layer ----------------

// 80 edges/block (5 tiles of 16). Per tile, per wave(=head):
// acc = hb[s]@wl + hb[n]@wr + efc[p]@we (6 chained MFMAs / t); epilogue adds biases,
// leaky, dot att, 16-lane reduce -> lg[head][p].
__global__ __launch_bounds__(256) void k_elog(
    const short* __restrict__ hb, const short* __restrict__ efc,
    const int* __restrict__ psrc, const int* __restrict__ pdst,
    const short* __restrict__ wlf, const short* __restrict__ wrf,
    const short* __restrict__ wef, const float* __restrict__ bl,
    const float* __restrict__ br, const float* __restrict__ att, float* __restrict__ lg) {
  int tid = threadIdx.x;
  int w = tid >> 6, lane = tid & 63, q = lane & 15, g = lane >> 4;
  int cbase = w * 64;
  bf16x8 Bl[4][2], Br[4][2], Be[4][2];
  float av[4], bv[4];
#pragma unroll
  for (int t = 0; t < 4; ++t) {
    int c = cbase + t * 16 + q;
    av[t] = att[c];
    bv[t] = bl[c] + br[c];
#pragma unroll
    for (int kh = 0; kh < 2; ++kh) {
      size_t fo = ((size_t)((w * 4 + t) * 2 + kh) * 64 + lane) * 8;
      Bl[t][kh] = *(const bf16x8*)(wlf + fo);
      Br[t][kh] = *(const bf16x8*)(wrf + fo);
      Be[t][kh] = *(const bf16x8*)(wef + fo);
    }
  }
  int pb = blockIdx.x * 80;
#pragma unroll 1
  for (int tile = 0; tile < 5; ++tile) {
    int p0 = pb + tile * 16;
    int pq = p0 + q;
    int sq = psrc[pq], nq = pdst[pq];
    const short* as = hb + (size_t)sq * 64;
    const short* ar = hb + (size_t)nq * 64;
    const short* ae = efc + (size_t)pq * 64;
    bf16x8 As0 = *(const bf16x8*)(as + g * 8);
    bf16x8 As1 = *(const bf16x8*)(as + 32 + g * 8);
    bf16x8 Ar0 = *(const bf16x8*)(ar + g * 8);
    bf16x8 Ar1 = *(const bf16x8*)(ar + 32 + g * 8);
    bf16x8 Ae0 = *(const bf16x8*)(ae + g * 8);
    bf16x8 Ae1 = *(const bf16x8*)(ae + 32 + g * 8);
    f32x4 acc[4];
#pragma unroll
    for (int t = 0; t < 4; ++t) {
      f32x4 z = {0.f, 0.f, 0.f, 0.f};
      z = mfma16(As0, Bl[t][0], z);
      z = mfma16(As1, Bl[t][1], z);
      z = mfma16(Ar0, Br[t][0], z);
      z = mfma16(Ar1, Br[t][1], z);
      z = mfma16(Ae0, Be[t][0], z);
      acc[t] = mfma16(Ae1, Be[t][1], z);
    }
#pragma unroll
    for (int r = 0; r < 4; ++r) {
      float pd = 0.f;
#pragma unroll
      for (int t = 0; t < 4; ++t) {
        float m = acc[t][r] + bv[t];
        m = m > 0.f ? m : 0.2f * m;
        pd += m * av[t];
      }
      pd += __shfl_xor(pd, 1, 64);
      pd += __shfl_xor(pd, 2, 64);
      pd += __shfl_xor(pd, 4, 64);
      pd += __shfl_xor(pd, 8, 64);
      if (q == 0) lg[(size_t)w * EP + p0 + g * 4 + r] = pd;
    }
  }
}

// per dst node: softmax + 8-edge-parallel weighted gather of hb[src] -> aggb[n][h*64+k]
__global__ __launch_bounds__(256) void k_agg(
    const short* __restrict__ hb, const float* __restrict__ lg,
    const int* __restrict__ row_ptr, const int* __restrict__ psrc,
    short* __restrict__ aggb) {
  int tid = threadIdx.x, lane = tid & 63, hw = tid >> 6;
  int n = blockIdx.x;
  int s0 = row_ptr[n], s1 = row_ptr[n + 1];
  const float* lgh = lg + (size_t)hw * EP;
  float m = -3.4e38f;
  for (int i = s0 + lane; i < s1; i += 64) m = fmaxf(m, lgh[i]);
  m = wred_max(m);
  float sum = 0.f;
  for (int i = s0 + lane; i < s1; i += 64) sum += __expf(lgh[i] - m);
  sum = wred_sum(sum);
  float inv = 1.f / sum;
  int e8 = lane >> 3, oct = lane & 7;
  float acc[8];
#pragma unroll
  for (int j = 0; j < 8; ++j) acc[j] = 0.f;
  for (int p0 = s0; p0 < s1; p0 += 8) {
    int p = p0 + e8;
    bool v = p < s1;
    int pc = v ? p : s1 - 1;
    int sp = psrc[pc];
    float al = v ? __expf(lgh[pc] - m) * inv : 0.f;
    bf16x8 A = *(const bf16x8*)(hb + (size_t)sp * 64 + oct * 8);
#pragma unroll
    for (int j = 0; j < 8; ++j) acc[j] += al * b2f(A[j]);
  }
#pragma unroll
  for (int j = 0; j < 8; ++j) {
    acc[j] += __shfl_xor(acc[j], 8, 64);
    acc[j] += __shfl_xor(acc[j], 16, 64);
    acc[j] += __shfl_xor(acc[j], 32, 64);
  }
  if (lane < 8) {
    bf16x8 o;
#pragma unroll
    for (int j = 0; j < 8; ++j) o[j] = f2bf(acc[j]);
    *(bf16x8*)(aggb + (size_t)n * 256 + hw * 64 + lane * 8) = o;
  }
}

// h += relu(aggb @ Wfold + bfold); hb = bf16(h). 16 nodes/block, wave w -> cols w*16..+16
__global__ __launch_bounds__(256) void k_upd(
    const short* __restrict__ aggb, const short* __restrict__ updf,
    const float* __restrict__ bl, const float* __restrict__ bias,
    float* __restrict__ h, short* __restrict__ hb) {
  int tid = threadIdx.x;
  int w = tid >> 6, lane = tid & 63, q = lane & 15, g = lane >> 4;
  int n0 = blockIdx.x * 16;
  const short* arow = aggb + (size_t)(n0 + q) * 256;
  f32x4 z = {0.f, 0.f, 0.f, 0.f};
#pragma unroll
  for (int kh = 0; kh < 8; ++kh) {
    bf16x8 A = *(const bf16x8*)(arow + kh * 32 + g * 8);
    bf16x8 B = *(const bf16x8*)(updf + ((size_t)(w * 8 + kh) * 64 + lane) * 8);
    z = mfma16(A, B, z);
  }
  int c = w * 16 + q;
  float bf = 0.25f * (bl[c] + bl[64 + c] + bl[128 + c] + bl[192 + c]) + bias[c];
#pragma unroll
  for (int r = 0; r < 4; ++r) {
    int n = n0 + g * 4 + r;
    float nh = h[(size_t)n * 64 + c] + fmaxf(z[r] + bf, 0.f);
    h[(size_t)n * 64 + c] = nh;
    hb[(size_t)n * 64 + c] = f2bf(nh);
  }
}

// ---------------- output heads ----------------

// 64 edges/block (4 tiles); B frags register-resident across tiles.
__global__ __launch_bounds__(256) void k_ecls(
    const short* __restrict__ hb, const short* __restrict__ efc,
    const int* __restrict__ src, const int* __restrict__ dst,
    const int* __restrict__ pos, const short* __restrict__ eclsf,
    const float* __restrict__ b1, const float* __restrict__ w2,
    const float* __restrict__ b2, float* __restrict__ out) {
  __shared__ float sm[64];
  int tid = threadIdx.x;
  int w = tid >> 6, lane = tid & 63, q = lane & 15, g = lane >> 4;
  int c = w * 16 + q;
  bf16x8 Bf[6];
#pragma unroll
  for (int kh = 0; kh < 6; ++kh)
    Bf[kh] = *(const bf16x8*)(eclsf + ((size_t)(w * 6 + kh) * 64 + lane) * 8);
  float b1v = b1[c], w2v = w2[c], b2v = b2[0];
#pragma unroll 1
  for (int tile = 0; tile < 4; ++tile) {
    int e0 = blockIdx.x * 64 + tile * 16;
    int eq = e0 + q;
    int sq = src[eq], dq = dst[eq], pq = pos[eq];
    const short* hs = hb + (size_t)sq * 64;
    const short* hd = hb + (size_t)dq * 64;
    const short* ee = efc + (size_t)pq * 64;
    f32x4 acc = {0.f, 0.f, 0.f, 0.f};
    acc = mfma16(*(const bf16x8*)(hs + g * 8), Bf[0], acc);
    acc = mfma16(*(const bf16x8*)(hs + 32 + g * 8), Bf[1], acc);
    acc = mfma16(*(const bf16x8*)(hd + g * 8), Bf[2], acc);
    acc = mfma16(*(const bf16x8*)(hd + 32 + g * 8), Bf[3], acc);
    acc = mfma16(*(const bf16x8*)(ee + g * 8), Bf[4], acc);
    acc = mfma16(*(const bf16x8*)(ee + 32 + g * 8), Bf[5], acc);
#pragma unroll
    for (int r = 0; r < 4; ++r) {
      float hv = fmaxf(acc[r] + b1v, 0.f) * w2v;
      hv += __shfl_xor(hv, 1, 64);
      hv += __shfl_xor(hv, 2, 64);
      hv += __shfl_xor(hv, 4, 64);
      hv += __shfl_xor(hv, 8, 64);
      if (q == 0) sm[w * 16 + g * 4 + r] = hv;
    }
    __syncthreads();
    if (tid < 16) {
      float t = sm[tid] + sm[16 + tid] + sm[32 + tid] + sm[48 + tid] + b2v;
      out[e0 + tid] = 1.f / (1.f + __expf(-t));
    }
    __syncthreads();
  }
}

__global__ __launch_bounds__(256) void k_offset(
    const float* __restrict__ h, const float* __restrict__ w1, const float* __restrict__ b1,
    const float* __restrict__ w2, const float* __restrict__ b2, float* __restrict__ out) {
  __shared__ float w1l[4096];
  int tid = threadIdx.x;
#pragma unroll
  for (int q = 0; q < 16; ++q) w1l[q * 256 + tid] = w1[q * 256 + tid];
  __syncthreads();
  int lane = tid & 63, g = tid >> 6;
  int n = blockIdx.x * 4 + g;
  float hr = h[n * 64 + lane];
  float hid = b1[lane];
#pragma unroll
  for (int k = 0; k < 64; ++k) hid += bcast(hr, k) * w1l[k * 64 + lane];
  hid = fmaxf(hid, 0.f);
  float p0 = wred_sum(hid * w2[lane * 2]);
  float p1 = wred_sum(hid * w2[lane * 2 + 1]);
  if (lane == 0) {
    out[N_EDGES + n * 2] = p0 + b2[0];
    out[N_EDGES + n * 2 + 1] = p1 + b2[1];
  }
}

// ---------------- launcher ----------------

extern "C" void kernel_launch(void* const* d_in, const int* in_sizes, int n_in,
                              void* d_out, int out_size, void* d_ws, size_t ws_size,
                              hipStream_t stream) {
  const float* x     = (const float*)d_in[0];
  const int*   eidx  = (const int*)d_in[1];
  const float* eattr = (const float*)d_in[2];
  const float* ne_w1 = (const float*)d_in[3];
  const float* ne_b1 = (const float*)d_in[4];
  const float* ne_w2 = (const float*)d_in[5];
  const float* ne_b2 = (const float*)d_in[6];
  const float* ee_w1 = (const float*)d_in[7];
  const float* ee_b1 = (const float*)d_in[8];
  const float* ee_w2 = (const float*)d_in[9];
  const float* ee_b2 = (const float*)d_in[10];
  const float* cv_wl = (const float*)d_in[11];
  const float* cv_bl = (const float*)d_in[12];
  const float* cv_wr = (const float*)d_in[13];
  const float* cv_br = (const float*)d_in[14];
  const float* cv_we = (const float*)d_in[15];
  const float* cv_att = (const float*)d_in[16];
  const float* cv_bias = (const float*)d_in[17];
  const float* ec_w1 = (const float*)d_in[18];
  const float* ec_b1 = (const float*)d_in[19];
  const float* ec_w2 = (const float*)d_in[20];
  const float* ec_b2 = (const float*)d_in[21];
  const float* or_w1 = (const float*)d_in[22];
  const float* or_b1 = (const float*)d_in[23];
  const float* or_w2 = (const float*)d_in[24];
  const float* or_b2 = (const float*)d_in[25];

  const int* src = eidx;
  const int* dst = eidx + N_EDGES;

  // workspace layout
  float* fws = (float*)d_ws;
  size_t o = 0;
  float* h  = fws + o; o += (size_t)N_NODES * 64;
  float* lg = fws + o; o += (size_t)EP * 4;
  short* sws = (short*)(fws + o);
  size_t so = 0;
  short* hb   = sws + so; so += (size_t)N_NODES * 64;
  short* aggb = sws + so; so += (size_t)N_NODES * 256;
  short* efc  = sws + so; so += (size_t)EP * 64;
  short* wlf  = sws + so; so += 3 * PREP_SEG;
  short* wrf  = sws + so; so += 3 * PREP_SEG;
  short* wef  = sws + so; so += 3 * PREP_SEG;
  short* updf = sws + so; so += 3 * PREP_SEG;
  short* eclsf = sws + so; so += 12288;
  short* encf  = sws + so; so += 4096;
  int* iws = (int*)(sws + so + (so & 1));
  int* row_ptr = iws;
  int* col_idx = iws + (N_NODES + 64);
  int* pdst = col_idx + EP;
  int* psrc = pdst + EP;
  int* pos  = psrc + EP;
  int* cnt  = pos + EP;
  int* fill = cnt + N_NODES;
  int* bsum = fill + N_NODES;
  int* boff = bsum + 128;

  float* out = (float*)d_out;

  // weight fragment prep
  k_prep_all<<<(12 * PREP_SEG + 12288 + 4096 + 255) / 256, 256, 0, stream>>>(
      cv_wl, cv_wr, cv_we, ec_w1, ee_w2, wlf, wrf, wef, updf, eclsf, encf);

  // CSR build
  k_zero<<<(N_NODES + 255) / 256, 256, 0, stream>>>(cnt, fill);
  k_count<<<(N_EDGES + 255) / 256, 256, 0, stream>>>(dst, cnt);
  k_scan1<<<NBLK, 256, 0, stream>>>(cnt, row_ptr, bsum);
  k_scan2<<<1, 256, 0, stream>>>(bsum, boff);
  k_scan3<<<NBLK, 256, 0, stream>>>(boff, row_ptr);
  k_scatter<<<(EP + 255) / 256, 256, 0, stream>>>(dst, row_ptr, fill, col_idx, pdst);
  k_sort<<<(N_NODES + 255) / 256, 256, 0, stream>>>(row_ptr, col_idx);
  k_psrc<<<(EP + 255) / 256, 256, 0, stream>>>(col_idx, pdst, src, psrc, pos);

  // encoders
  k_node_enc<<<N_NODES / 4, 256, 0, stream>>>(x, ne_w1, ne_b1, ne_w2, ne_b2, h, hb);
  k_edge_enc<<<N_EDGES / 16, 256, 0, stream>>>(eattr, ee_w1, ee_b1, encf, ee_b2, pos, efc);
  k_loop_feat<<<N_NODES / 4, 256, 0, stream>>>(row_ptr, efc);

  // 3 GATv2 layers
  for (int l = 0; l < 3; ++l) {
    const float* bl = cv_bl + (size_t)l * 256;
    const float* br = cv_br + (size_t)l * 256;
    const float* at = cv_att + (size_t)l * 256;
    const float* bi = cv_bias + (size_t)l * 64;
    k_elog<<<EP / 80, 256, 0, stream>>>(hb, efc, psrc, pdst,
                                        wlf + (size_t)l * PREP_SEG,
                                        wrf + (size_t)l * PREP_SEG,
                                        wef + (size_t)l * PREP_SEG, bl, br, at, lg);
    k_agg<<<N_NODES, 256, 0, stream>>>(hb, lg, row_ptr, psrc, aggb);
    k_upd<<<N_NODES / 16, 256, 0, stream>>>(aggb, updf + (size_t)l * PREP_SEG, bl, bi, h, hb);
  }

  // heads
  k_ecls<<<N_EDGES / 64, 256, 0, stream>>>(hb, efc, src, dst, pos, eclsf,
                                           ec_b1, ec_w2, ec_b2, out);
  k_offset<<<N_NODES / 4, 256, 0, stream>>>(h, or_w1, or_b1, or_w2, or_b2, out);
}

// Round 5
// 385.660 us; speedup vs baseline: 5.1758x; 1.1430x over previous
//
#include <hip/hip_runtime.h>

#define N_NODES 20000
#define N_EDGES 160000
#define EP (N_EDGES + N_NODES)   // 180000 edges incl. self loops
#define NBLK ((N_NODES + 255) / 256)  // 79
#define PREP_SEG 16384

typedef __attribute__((ext_vector_type(8))) short bf16x8;
typedef __attribute__((ext_vector_type(4))) float f32x4;

__device__ __forceinline__ short f2bf(float f) {
  unsigned u = __float_as_uint(f);
  unsigned r = (u + 0x7FFFu + ((u >> 16) & 1u)) >> 16;  // RNE
  return (short)r;
}
__device__ __forceinline__ float b2f(short s) {
  return __uint_as_float(((unsigned)(unsigned short)s) << 16);
}

__device__ __forceinline__ f32x4 mfma16(bf16x8 a, bf16x8 b, f32x4 c) {
  return __builtin_amdgcn_mfma_f32_16x16x32_bf16(a, b, c, 0, 0, 0);
}

__device__ __forceinline__ float bcast(float v, int k) {
  return __uint_as_float(__builtin_amdgcn_readlane(__float_as_uint(v), k));
}

__device__ __forceinline__ float wred_sum(float v) {
#pragma unroll
  for (int o = 32; o > 0; o >>= 1) v += __shfl_xor(v, o, 64);
  return v;
}

// ---------------- weight fragment prep (bf16, MFMA frag order) ----------------
__global__ void k_prep_all(const float* __restrict__ cv_wl, const float* __restrict__ cv_wr,
                           const float* __restrict__ cv_we, const float* __restrict__ ec_w1,
                           const float* __restrict__ ee_w2,
                           short* __restrict__ wlf, short* __restrict__ wrf,
                           short* __restrict__ wef, short* __restrict__ updf,
                           short* __restrict__ eclsf, short* __restrict__ encf) {
  int i = blockIdx.x * 256 + threadIdx.x;
  if (i < 12 * PREP_SEG) {
    int grp = i / PREP_SEG;
    int r = i % PREP_SEG;
    int kind = grp / 3, l = grp % 3;
    int j = r & 7, lane = (r >> 3) & 63;
    int q = lane & 15, g = lane >> 4;
    if (kind < 3) {  // wl/wr/we : [64,256], out cols c = w*64+t*16+q
      int kh = (r >> 9) & 1, t = (r >> 10) & 3, w = r >> 12;
      int k = kh * 32 + g * 8 + j, c = w * 64 + t * 16 + q;
      const float* W = (kind == 0 ? cv_wl : kind == 1 ? cv_wr : cv_we) + (size_t)l * 64 * 256;
      short* out = (kind == 0 ? wlf : kind == 1 ? wrf : wef) + (size_t)l * PREP_SEG;
      out[r] = f2bf(W[k * 256 + c]);
    } else {        // folded update: Wfold[h*64+kk][c] = 0.25*wl[kk][h*64+c], K=256, Ncol=64
      int kh = (r >> 9) & 7, w = r >> 12;
      int k = kh * 32 + g * 8 + j, c = w * 16 + q;
      const float* W = cv_wl + (size_t)l * 64 * 256;
      updf[(size_t)l * PREP_SEG + r] = f2bf(0.25f * W[(k & 63) * 256 + (k >> 6) * 64 + c]);
    }
  } else if (i < 12 * PREP_SEG + 12288) {  // ec_w1 [192,64], 6 k-frags
    int r = i - 12 * PREP_SEG;
    int j = r & 7, lane = (r >> 3) & 63, f = r >> 9;
    int w = f / 6, kh = f % 6;
    int q = lane & 15, g = lane >> 4;
    int k = kh * 32 + g * 8 + j, c = w * 16 + q;
    eclsf[r] = f2bf(ec_w1[(size_t)k * 64 + c]);
  } else {                                  // ee_w2 [64,64], 2 k-frags
    int r = i - 12 * PREP_SEG - 12288;
    if (r >= 4096) return;
    int j = r & 7, lane = (r >> 3) & 63, f = r >> 9;
    int w = f >> 1, kh = f & 1;
    int q = lane & 15, g = lane >> 4;
    int k = kh * 32 + g * 8 + j, c = w * 16 + q;
    encf[r] = f2bf(ee_w2[(size_t)k * 64 + c]);
  }
}

// ---------------- CSR build ----------------

__global__ void k_zero(int* __restrict__ cnt, int* __restrict__ fill) {
  int i = blockIdx.x * blockDim.x + threadIdx.x;
  if (i < N_NODES) { cnt[i] = 0; fill[i] = 0; }
}

__global__ void k_count(const int* __restrict__ dst, int* __restrict__ cnt) {
  int i = blockIdx.x * blockDim.x + threadIdx.x;
  if (i < N_EDGES) atomicAdd(&cnt[dst[i]], 1);
}

__global__ void k_scan1(const int* __restrict__ cnt, int* __restrict__ row_ptr,
                        int* __restrict__ bsum) {
  __shared__ int sh[256];
  int t = threadIdx.x, b = blockIdx.x, i = b * 256 + t;
  int v = (i < N_NODES) ? cnt[i] + 1 : 0;  // +1 self loop
  sh[t] = v;
  __syncthreads();
#pragma unroll
  for (int off = 1; off < 256; off <<= 1) {
    int x = (t >= off) ? sh[t - off] : 0;
    __syncthreads();
    sh[t] += x;
    __syncthreads();
  }
  if (i < N_NODES) row_ptr[i + 1] = sh[t];
  if (t == 255) bsum[b] = sh[255];
}

__global__ void k_scan2(const int* __restrict__ bsum, int* __restrict__ boff) {
  __shared__ int sh[256];
  int t = threadIdx.x;
  int v = (t < NBLK) ? bsum[t] : 0;
  sh[t] = v;
  __syncthreads();
#pragma unroll
  for (int off = 1; off < 256; off <<= 1) {
    int x = (t >= off) ? sh[t - off] : 0;
    __syncthreads();
    sh[t] += x;
    __syncthreads();
  }
  if (t < NBLK) boff[t] = sh[t] - v;  // exclusive
}

__global__ void k_scan3(const int* __restrict__ boff, int* __restrict__ row_ptr) {
  int t = threadIdx.x, b = blockIdx.x, i = b * 256 + t;
  if (i < N_NODES) row_ptr[i + 1] += boff[b];
  if (i == 0) row_ptr[0] = 0;
}

__global__ void k_scatter(const int* __restrict__ dst, const int* __restrict__ row_ptr,
                          int* __restrict__ fill, int* __restrict__ col_idx,
                          int* __restrict__ pdst) {
  int i = blockIdx.x * blockDim.x + threadIdx.x;
  if (i >= EP) return;
  int d = (i < N_EDGES) ? dst[i] : (i - N_EDGES);
  int p = row_ptr[d] + atomicAdd(&fill[d], 1);
  col_idx[p] = i;
  pdst[p] = d;
}

__global__ void k_sort(const int* __restrict__ row_ptr, int* __restrict__ col_idx) {
  int n = blockIdx.x * blockDim.x + threadIdx.x;
  if (n >= N_NODES) return;
  int s = row_ptr[n], e = row_ptr[n + 1];
  for (int i = s + 1; i < e; ++i) {
    int v = col_idx[i];
    int j = i - 1;
    while (j >= s && col_idx[j] > v) { col_idx[j + 1] = col_idx[j]; --j; }
    col_idx[j + 1] = v;
  }
}

// after sort: psrc[p] = source node of CSR slot p; pos[eid] = CSR slot of edge eid
__global__ void k_psrc(const int* __restrict__ col_idx, const int* __restrict__ pdst,
                       const int* __restrict__ src, int* __restrict__ psrc,
                       int* __restrict__ pos) {
  int p = blockIdx.x * 256 + threadIdx.x;
  if (p >= EP) return;
  int eid = col_idx[p];
  pos[eid] = p;
  psrc[p] = (eid < N_EDGES) ? src[eid] : (eid - N_EDGES);
}

// ---------------- encoders ----------------

__global__ __launch_bounds__(256) void k_node_enc(
    const float* __restrict__ x, const float* __restrict__ w1, const float* __restrict__ b1,
    const float* __restrict__ w2, const float* __restrict__ b2,
    float* __restrict__ h, short* __restrict__ hb) {
  __shared__ float w2l[4096];
  int tid = threadIdx.x;
#pragma unroll
  for (int q = 0; q < 16; ++q) w2l[q * 256 + tid] = w2[q * 256 + tid];
  __syncthreads();
  int lane = tid & 63, g = tid >> 6;
  int n = blockIdx.x * 4 + g;
  float x0 = x[n * 2], x1 = x[n * 2 + 1];
  float hid = fmaxf(x0 * w1[lane] + x1 * w1[64 + lane] + b1[lane], 0.f);
  float out = b2[lane];
#pragma unroll
  for (int k = 0; k < 64; ++k) out += bcast(hid, k) * w2l[k * 64 + lane];
  h[n * 64 + lane] = out;
  hb[n * 64 + lane] = f2bf(out);
}

// 16 edges/block: layer1 on VALU -> LDS bf16, layer2 via MFMA; LDS-staged
// output tile then 128B-contiguous row scatter into efc (CSR order via pos).
__global__ __launch_bounds__(256) void k_edge_enc(
    const float* __restrict__ ea, const float* __restrict__ w1, const float* __restrict__ b1,
    const short* __restrict__ encf, const float* __restrict__ b2,
    const int* __restrict__ pos, short* __restrict__ efc) {
  __shared__ short hs[16 * 72];
  __shared__ short ot[16 * 64];
  __shared__ int ps[16];
  int tid = threadIdx.x;
  int w = tid >> 6, lane = tid & 63, q = lane & 15, g = lane >> 4;
  int e0 = blockIdx.x * 16;
  if (tid < 16) ps[tid] = pos[e0 + tid];
#pragma unroll
  for (int t = 0; t < 4; ++t) {
    int e = e0 + w * 4 + t;
    float a0 = ea[e * 3], a1 = ea[e * 3 + 1], a2 = ea[e * 3 + 2];
    float hid = fmaxf(a0 * w1[lane] + a1 * w1[64 + lane] + a2 * w1[128 + lane] + b1[lane], 0.f);
    hs[(w * 4 + t) * 72 + lane] = f2bf(hid);
  }
  __syncthreads();
  bf16x8 A0 = *(const bf16x8*)&hs[q * 72 + g * 8];
  bf16x8 A1 = *(const bf16x8*)&hs[q * 72 + 32 + g * 8];
  bf16x8 B0 = *(const bf16x8*)(encf + ((size_t)(w * 2 + 0) * 64 + lane) * 8);
  bf16x8 B1 = *(const bf16x8*)(encf + ((size_t)(w * 2 + 1) * 64 + lane) * 8);
  f32x4 z = {0.f, 0.f, 0.f, 0.f};
  z = mfma16(A0, B0, z);
  z = mfma16(A1, B1, z);
  int c = w * 16 + q;
  float bv = b2[c];
#pragma unroll
  for (int r = 0; r < 4; ++r) ot[(g * 4 + r) * 64 + c] = f2bf(z[r] + bv);
  __syncthreads();
  int row = tid >> 4, part = tid & 15;
  *(short4*)(efc + (size_t)ps[row] * 64 + part * 4) = *(const short4*)(ot + row * 64 + part * 4);
}

// self-loop row (last CSR slot per node) = mean of node's original-edge rows; 8-row parallel
__global__ __launch_bounds__(256) void k_loop_feat(
    const int* __restrict__ row_ptr, short* __restrict__ efc) {
  int tid = threadIdx.x, lane = tid & 63, w = tid >> 6;
  int n = blockIdx.x * 4 + w;
  int s = row_ptr[n], e1 = row_ptr[n + 1];
  int r8 = lane >> 3, oct = lane & 7;
  float acc[8];
#pragma unroll
  for (int j = 0; j < 8; ++j) acc[j] = 0.f;
  for (int p0 = s; p0 < e1 - 1; p0 += 8) {
    int p = p0 + r8;
    if (p < e1 - 1) {
      bf16x8 A = *(const bf16x8*)(efc + (size_t)p * 64 + oct * 8);
#pragma unroll
      for (int j = 0; j < 8; ++j) acc[j] += b2f(A[j]);
    }
  }
#pragma unroll
  for (int j = 0; j < 8; ++j) {
    acc[j] += __shfl_xor(acc[j], 8, 64);
    acc[j] += __shfl_xor(acc[j], 16, 64);
    acc[j] += __shfl_xor(acc[j], 32, 64);
  }
  int c = e1 - 1 - s;
  float invc = 1.f / (float)(c > 0 ? c : 1);
  if (lane < 8) {
    bf16x8 o8;
#pragma unroll
    for (int j = 0; j < 8; ++j) o8[j] = f2bf(acc[j] * invc);
    *(bf16x8*)(efc + (size_t)(e1 - 1) * 64 + lane * 8) = o8;
  }
}

// ---------------- GAT layer ----------------

// 80 CSR slots/block, 5 tiles of 16, software-pipelined A gathers (1-deep).
// Per wave(=head): acc = hb[s]@wl + hb[n]@wr + efc[p]@we; epilogue -> lg[p][head].
__global__ __launch_bounds__(256) void k_elog(
    const short* __restrict__ hb, const short* __restrict__ efc,
    const int* __restrict__ psrc, const int* __restrict__ pdst,
    const short* __restrict__ wlf, const short* __restrict__ wrf,
    const short* __restrict__ wef, const float* __restrict__ bl,
    const float* __restrict__ br, const float* __restrict__ att, float* __restrict__ lg) {
  int tid = threadIdx.x;
  int w = tid >> 6, lane = tid & 63, q = lane & 15, g = lane >> 4;
  int cbase = w * 64;
  bf16x8 Bl[4][2], Br[4][2], Be[4][2];
  float av[4], bv[4];
#pragma unroll
  for (int t = 0; t < 4; ++t) {
    int c = cbase + t * 16 + q;
    av[t] = att[c];
    bv[t] = bl[c] + br[c];
#pragma unroll
    for (int kh = 0; kh < 2; ++kh) {
      size_t fo = ((size_t)((w * 4 + t) * 2 + kh) * 64 + lane) * 8;
      Bl[t][kh] = *(const bf16x8*)(wlf + fo);
      Br[t][kh] = *(const bf16x8*)(wrf + fo);
      Be[t][kh] = *(const bf16x8*)(wef + fo);
    }
  }
  int pb = blockIdx.x * 80;
  int sidx[5], nidx[5];
#pragma unroll
  for (int t5 = 0; t5 < 5; ++t5) {
    sidx[t5] = psrc[pb + t5 * 16 + q];
    nidx[t5] = pdst[pb + t5 * 16 + q];
  }
  bf16x8 A[2][6];
#define LOADA(buf, tl) {                                           \
    const short* as_ = hb + (size_t)sidx[tl] * 64;                 \
    const short* ar_ = hb + (size_t)nidx[tl] * 64;                 \
    const short* ae_ = efc + (size_t)(pb + (tl) * 16 + q) * 64;    \
    A[buf][0] = *(const bf16x8*)(as_ + g * 8);                     \
    A[buf][1] = *(const bf16x8*)(as_ + 32 + g * 8);                \
    A[buf][2] = *(const bf16x8*)(ar_ + g * 8);                     \
    A[buf][3] = *(const bf16x8*)(ar_ + 32 + g * 8);                \
    A[buf][4] = *(const bf16x8*)(ae_ + g * 8);                     \
    A[buf][5] = *(const bf16x8*)(ae_ + 32 + g * 8);                \
  }
  LOADA(0, 0)
#pragma unroll
  for (int tile = 0; tile < 5; ++tile) {
    const int buf = tile & 1;
    if (tile < 4) LOADA(buf ^ 1, tile + 1)
    f32x4 acc[4];
#pragma unroll
    for (int t = 0; t < 4; ++t) {
      f32x4 z = {0.f, 0.f, 0.f, 0.f};
      z = mfma16(A[buf][0], Bl[t][0], z);
      z = mfma16(A[buf][1], Bl[t][1], z);
      z = mfma16(A[buf][2], Br[t][0], z);
      z = mfma16(A[buf][3], Br[t][1], z);
      z = mfma16(A[buf][4], Be[t][0], z);
      acc[t] = mfma16(A[buf][5], Be[t][1], z);
    }
#pragma unroll
    for (int r = 0; r < 4; ++r) {
      float pd = 0.f;
#pragma unroll
      for (int t = 0; t < 4; ++t) {
        float m = acc[t][r] + bv[t];
        m = m > 0.f ? m : 0.2f * m;
        pd += m * av[t];
      }
      pd += __shfl_xor(pd, 1, 64);
      pd += __shfl_xor(pd, 2, 64);
      pd += __shfl_xor(pd, 4, 64);
      pd += __shfl_xor(pd, 8, 64);
      if (q == 0) lg[(size_t)(pb + tile * 16 + g * 4 + r) * 4 + w] = pd;
    }
  }
#undef LOADA
}

// per dst node (1 wave/node, 4 nodes/block): softmax (all 4 heads) + single-gather
// aggregation serving all heads -> aggb[n][h*64+k]
__global__ __launch_bounds__(256) void k_agg(
    const short* __restrict__ hb, const float* __restrict__ lg,
    const int* __restrict__ row_ptr, const int* __restrict__ psrc,
    short* __restrict__ aggb) {
  int tid = threadIdx.x, lane = tid & 63, w = tid >> 6;
  int n = blockIdx.x * 4 + w;
  int s0 = row_ptr[n], s1 = row_ptr[n + 1];
  int h4 = lane >> 4, i16 = lane & 15;
  float m = -3.4e38f;
  for (int p = s0 + i16; p < s1; p += 16) m = fmaxf(m, lg[(size_t)p * 4 + h4]);
#pragma unroll
  for (int o = 1; o < 16; o <<= 1) m = fmaxf(m, __shfl_xor(m, o, 64));
  float sum = 0.f;
  for (int p = s0 + i16; p < s1; p += 16) sum += __expf(lg[(size_t)p * 4 + h4] - m);
#pragma unroll
  for (int o = 1; o < 16; o <<= 1) sum += __shfl_xor(sum, o, 64);
  float inv = 1.f / sum;
  float mh[4], ih[4];
#pragma unroll
  for (int h = 0; h < 4; ++h) {
    mh[h] = __shfl(m, h * 16, 64);
    ih[h] = __shfl(inv, h * 16, 64);
  }
  int e8 = lane >> 3, oct = lane & 7;
  float acc[4][8];
#pragma unroll
  for (int h = 0; h < 4; ++h)
#pragma unroll
    for (int j = 0; j < 8; ++j) acc[h][j] = 0.f;
  for (int p0 = s0; p0 < s1; p0 += 8) {
    int p = p0 + e8;
    bool v = p < s1;
    int pc = v ? p : s1 - 1;
    int sp = psrc[pc];
    float4 L = *(const float4*)(lg + (size_t)pc * 4);
    bf16x8 A = *(const bf16x8*)(hb + (size_t)sp * 64 + oct * 8);
    float al[4];
    al[0] = v ? __expf(L.x - mh[0]) * ih[0] : 0.f;
    al[1] = v ? __expf(L.y - mh[1]) * ih[1] : 0.f;
    al[2] = v ? __expf(L.z - mh[2]) * ih[2] : 0.f;
    al[3] = v ? __expf(L.w - mh[3]) * ih[3] : 0.f;
#pragma unroll
    for (int h = 0; h < 4; ++h)
#pragma unroll
      for (int j = 0; j < 8; ++j) acc[h][j] += al[h] * b2f(A[j]);
  }
#pragma unroll
  for (int h = 0; h < 4; ++h)
#pragma unroll
    for (int j = 0; j < 8; ++j) {
      acc[h][j] += __shfl_xor(acc[h][j], 8, 64);
      acc[h][j] += __shfl_xor(acc[h][j], 16, 64);
      acc[h][j] += __shfl_xor(acc[h][j], 32, 64);
    }
  if (lane < 8) {
#pragma unroll
    for (int h = 0; h < 4; ++h) {
      bf16x8 o8;
#pragma unroll
      for (int j = 0; j < 8; ++j) o8[j] = f2bf(acc[h][j]);
      *(bf16x8*)(aggb + (size_t)n * 256 + h * 64 + lane * 8) = o8;
    }
  }
}

// h += relu(aggb @ Wfold + bfold); hb = bf16(h). 16 nodes/block, wave w -> cols w*16..+16
__global__ __launch_bounds__(256) void k_upd(
    const short* __restrict__ aggb, const short* __restrict__ updf,
    const float* __restrict__ bl, const float* __restrict__ bias,
    float* __restrict__ h, short* __restrict__ hb) {
  int tid = threadIdx.x;
  int w = tid >> 6, lane = tid & 63, q = lane & 15, g = lane >> 4;
  int n0 = blockIdx.x * 16;
  const short* arow = aggb + (size_t)(n0 + q) * 256;
  f32x4 z = {0.f, 0.f, 0.f, 0.f};
#pragma unroll
  for (int kh = 0; kh < 8; ++kh) {
    bf16x8 A = *(const bf16x8*)(arow + kh * 32 + g * 8);
    bf16x8 B = *(const bf16x8*)(updf + ((size_t)(w * 8 + kh) * 64 + lane) * 8);
    z = mfma16(A, B, z);
  }
  int c = w * 16 + q;
  float bf = 0.25f * (bl[c] + bl[64 + c] + bl[128 + c] + bl[192 + c]) + bias[c];
#pragma unroll
  for (int r = 0; r < 4; ++r) {
    int n = n0 + g * 4 + r;
    float nh = h[(size_t)n * 64 + c] + fmaxf(z[r] + bf, 0.f);
    h[(size_t)n * 64 + c] = nh;
    hb[(size_t)n * 64 + c] = f2bf(nh);
  }
}

// ---------------- output heads ----------------

// 64 edges/block (4 tiles), pipelined A gathers, single barrier.
__global__ __launch_bounds__(256) void k_ecls(
    const short* __restrict__ hb, const short* __restrict__ efc,
    const int* __restrict__ src, const int* __restrict__ dst,
    const int* __restrict__ pos, const short* __restrict__ eclsf,
    const float* __restrict__ b1, const float* __restrict__ w2,
    const float* __restrict__ b2, float* __restrict__ out) {
  __shared__ float sm[256];
  int tid = threadIdx.x;
  int w = tid >> 6, lane = tid & 63, q = lane & 15, g = lane >> 4;
  int c = w * 16 + q;
  bf16x8 Bf[6];
#pragma unroll
  for (int kh = 0; kh < 6; ++kh)
    Bf[kh] = *(const bf16x8*)(eclsf + ((size_t)(w * 6 + kh) * 64 + lane) * 8);
  float b1v = b1[c], w2v = w2[c], b2v = b2[0];
  int e0b = blockIdx.x * 64;
  int sq[4], dq[4], pq[4];
#pragma unroll
  for (int t = 0; t < 4; ++t) {
    int e = e0b + t * 16 + q;
    sq[t] = src[e];
    dq[t] = dst[e];
    pq[t] = pos[e];
  }
  bf16x8 A[2][6];
#define LOADE(buf, tl) {                                          \
    const short* hs_ = hb + (size_t)sq[tl] * 64;                  \
    const short* hd_ = hb + (size_t)dq[tl] * 64;                  \
    const short* ee_ = efc + (size_t)pq[tl] * 64;                 \
    A[buf][0] = *(const bf16x8*)(hs_ + g * 8);                    \
    A[buf][1] = *(const bf16x8*)(hs_ + 32 + g * 8);               \
    A[buf][2] = *(const bf16x8*)(hd_ + g * 8);                    \
    A[buf][3] = *(const bf16x8*)(hd_ + 32 + g * 8);               \
    A[buf][4] = *(const bf16x8*)(ee_ + g * 8);                    \
    A[buf][5] = *(const bf16x8*)(ee_ + 32 + g * 8);               \
  }
  LOADE(0, 0)
#pragma unroll
  for (int tile = 0; tile < 4; ++tile) {
    const int buf = tile & 1;
    if (tile < 3) LOADE(buf ^ 1, tile + 1)
    f32x4 acc = {0.f, 0.f, 0.f, 0.f};
    acc = mfma16(A[buf][0], Bf[0], acc);
    acc = mfma16(A[buf][1], Bf[1], acc);
    acc = mfma16(A[buf][2], Bf[2], acc);
    acc = mfma16(A[buf][3], Bf[3], acc);
    acc = mfma16(A[buf][4], Bf[4], acc);
    acc = mfma16(A[buf][5], Bf[5], acc);
#pragma unroll
    for (int r = 0; r < 4; ++r) {
      float hv = fmaxf(acc[r] + b1v, 0.f) * w2v;
      hv += __shfl_xor(hv, 1, 64);
      hv += __shfl_xor(hv, 2, 64);
      hv += __shfl_xor(hv, 4, 64);
      hv += __shfl_xor(hv, 8, 64);
      if (q == 0) sm[tile * 64 + w * 16 + g * 4 + r] = hv;
    }
  }
#undef LOADE
  __syncthreads();
  if (tid < 64) {
    int tile = tid >> 4, e = tid & 15;
    float t = sm[tile * 64 + e] + sm[tile * 64 + 16 + e] +
              sm[tile * 64 + 32 + e] + sm[tile * 64 + 48 + e] + b2v;
    out[e0b + tile * 16 + e] = 1.f / (1.f + __expf(-t));
  }
}

__global__ __launch_bounds__(256) void k_offset(
    const float* __restrict__ h, const float* __restrict__ w1, const float* __restrict__ b1,
    const float* __restrict__ w2, const float* __restrict__ b2, float* __restrict__ out) {
  __shared__ float w1l[4096];
  int tid = threadIdx.x;
#pragma unroll
  for (int q = 0; q < 16; ++q) w1l[q * 256 + tid] = w1[q * 256 + tid];
  __syncthreads();
  int lane = tid & 63, g = tid >> 6;
  int n = blockIdx.x * 4 + g;
  float hr = h[n * 64 + lane];
  float hid = b1[lane];
#pragma unroll
  for (int k = 0; k < 64; ++k) hid += bcast(hr, k) * w1l[k * 64 + lane];
  hid = fmaxf(hid, 0.f);
  float p0 = wred_sum(hid * w2[lane * 2]);
  float p1 = wred_sum(hid * w2[lane * 2 + 1]);
  if (lane == 0) {
    out[N_EDGES + n * 2] = p0 + b2[0];
    out[N_EDGES + n * 2 + 1] = p1 + b2[1];
  }
}

// ---------------- launcher ----------------

extern "C" void kernel_launch(void* const* d_in, const int* in_sizes, int n_in,
                              void* d_out, int out_size, void* d_ws, size_t ws_size,
                              hipStream_t stream) {
  const float* x     = (const float*)d_in[0];
  const int*   eidx  = (const int*)d_in[1];
  const float* eattr = (const float*)d_in[2];
  const float* ne_w1 = (const float*)d_in[3];
  const float* ne_b1 = (const float*)d_in[4];
  const float* ne_w2 = (const float*)d_in[5];
  const float* ne_b2 = (const float*)d_in[6];
  const float* ee_w1 = (const float*)d_in[7];
  const float* ee_b1 = (const float*)d_in[8];
  const float* ee_w2 = (const float*)d_in[9];
  const float* ee_b2 = (const float*)d_in[10];
  const float* cv_wl = (const float*)d_in[11];
  const float* cv_bl = (const float*)d_in[12];
  const float* cv_wr = (const float*)d_in[13];
  const float* cv_br = (const float*)d_in[14];
  const float* cv_we = (const float*)d_in[15];
  const float* cv_att = (const float*)d_in[16];
  const float* cv_bias = (const float*)d_in[17];
  const float* ec_w1 = (const float*)d_in[18];
  const float* ec_b1 = (const float*)d_in[19];
  const float* ec_w2 = (const float*)d_in[20];
  const float* ec_b2 = (const float*)d_in[21];
  const float* or_w1 = (const float*)d_in[22];
  const float* or_b1 = (const float*)d_in[23];
  const float* or_w2 = (const float*)d_in[24];
  const float* or_b2 = (const float*)d_in[25];

  const int* src = eidx;
  const int* dst = eidx + N_EDGES;

  // workspace layout
  float* fws = (float*)d_ws;
  size_t o = 0;
  float* h  = fws + o; o += (size_t)N_NODES * 64;
  float* lg = fws + o; o += (size_t)EP * 4;   // layout [p][4]
  short* sws = (short*)(fws + o);
  size_t so = 0;
  short* hb   = sws + so; so += (size_t)N_NODES * 64;
  short* aggb = sws + so; so += (size_t)N_NODES * 256;
  short* efc  = sws + so; so += (size_t)EP * 64;
  short* wlf  = sws + so; so += 3 * PREP_SEG;
  short* wrf  = sws + so; so += 3 * PREP_SEG;
  short* wef  = sws + so; so += 3 * PREP_SEG;
  short* updf = sws + so; so += 3 * PREP_SEG;
  short* eclsf = sws + so; so += 12288;
  short* encf  = sws + so; so += 4096;
  int* iws = (int*)(sws + so + (so & 1));
  int* row_ptr = iws;
  int* col_idx = iws + (N_NODES + 64);
  int* pdst = col_idx + EP;
  int* psrc = pdst + EP;
  int* pos  = psrc + EP;
  int* cnt  = pos + EP;
  int* fill = cnt + N_NODES;
  int* bsum = fill + N_NODES;
  int* boff = bsum + 128;

  float* out = (float*)d_out;

  // weight fragment prep
  k_prep_all<<<(12 * PREP_SEG + 12288 + 4096 + 255) / 256, 256, 0, stream>>>(
      cv_wl, cv_wr, cv_we, ec_w1, ee_w2, wlf, wrf, wef, updf, eclsf, encf);

  // CSR build
  k_zero<<<(N_NODES + 255) / 256, 256, 0, stream>>>(cnt, fill);
  k_count<<<(N_EDGES + 255) / 256, 256, 0, stream>>>(dst, cnt);
  k_scan1<<<NBLK, 256, 0, stream>>>(cnt, row_ptr, bsum);
  k_scan2<<<1, 256, 0, stream>>>(bsum, boff);
  k_scan3<<<NBLK, 256, 0, stream>>>(boff, row_ptr);
  k_scatter<<<(EP + 255) / 256, 256, 0, stream>>>(dst, row_ptr, fill, col_idx, pdst);
  k_sort<<<(N_NODES + 255) / 256, 256, 0, stream>>>(row_ptr, col_idx);
  k_psrc<<<(EP + 255) / 256, 256, 0, stream>>>(col_idx, pdst, src, psrc, pos);

  // encoders
  k_node_enc<<<N_NODES / 4, 256, 0, stream>>>(x, ne_w1, ne_b1, ne_w2, ne_b2, h, hb);
  k_edge_enc<<<N_EDGES / 16, 256, 0, stream>>>(eattr, ee_w1, ee_b1, encf, ee_b2, pos, efc);
  k_loop_feat<<<N_NODES / 4, 256, 0, stream>>>(row_ptr, efc);

  // 3 GATv2 layers
  for (int l = 0; l < 3; ++l) {
    const float* bl = cv_bl + (size_t)l * 256;
    const float* br = cv_br + (size_t)l * 256;
    const float* at = cv_att + (size_t)l * 256;
    const float* bi = cv_bias + (size_t)l * 64;
    k_elog<<<EP / 80, 256, 0, stream>>>(hb, efc, psrc, pdst,
                                        wlf + (size_t)l * PREP_SEG,
                                        wrf + (size_t)l * PREP_SEG,
                                        wef + (size_t)l * PREP_SEG, bl, br, at, lg);
    k_agg<<<N_NODES / 4, 256, 0, stream>>>(hb, lg, row_ptr, psrc, aggb);
    k_upd<<<N_NODES / 16, 256, 0, stream>>>(aggb, updf + (size_t)l * PREP_SEG, bl, bi, h, hb);
  }

  // heads
  k_ecls<<<N_EDGES / 64, 256, 0, stream>>>(hb, efc, src, dst, pos, eclsf,
                                           ec_b1, ec_w2, ec_b2, out);
  k_offset<<<N_NODES / 4, 256, 0, stream>>>(h, or_w1, or_b1, or_w2, or_b2, out);
}

// Round 6
// 351.296 us; speedup vs baseline: 5.6821x; 1.0978x over previous
//
#include <hip/hip_runtime.h>

#define N_NODES 20000
#define N_EDGES 160000
#define EP (N_EDGES + N_NODES)   // 180000 edges incl. self loops
#define NBLK ((N_NODES + 255) / 256)  // 79
#define PREP_SEG 16384

typedef __attribute__((ext_vector_type(8))) short bf16x8;
typedef __attribute__((ext_vector_type(4))) float f32x4;

__device__ __forceinline__ short f2bf(float f) {
  unsigned u = __float_as_uint(f);
  unsigned r = (u + 0x7FFFu + ((u >> 16) & 1u)) >> 16;  // RNE
  return (short)r;
}
__device__ __forceinline__ float b2f(short s) {
  return __uint_as_float(((unsigned)(unsigned short)s) << 16);
}

__device__ __forceinline__ f32x4 mfma16(bf16x8 a, bf16x8 b, f32x4 c) {
  return __builtin_amdgcn_mfma_f32_16x16x32_bf16(a, b, c, 0, 0, 0);
}

__device__ __forceinline__ float bcast(float v, int k) {
  return __uint_as_float(__builtin_amdgcn_readlane(__float_as_uint(v), k));
}

__device__ __forceinline__ float wred_sum(float v) {
#pragma unroll
  for (int o = 32; o > 0; o >>= 1) v += __shfl_xor(v, o, 64);
  return v;
}

// async gather: per-lane global src -> linear LDS (base + lane*16)
__device__ __forceinline__ void gl16(const short* g, short* l) {
  __builtin_amdgcn_global_load_lds(
      (const __attribute__((address_space(1))) void*)g,
      (__attribute__((address_space(3))) void*)l, 16, 0, 0);
}

// ---------------- weight fragment prep (bf16, MFMA frag order) ----------------
__global__ void k_prep_all(const float* __restrict__ cv_wl, const float* __restrict__ cv_wr,
                           const float* __restrict__ cv_we, const float* __restrict__ ec_w1,
                           const float* __restrict__ ee_w2,
                           short* __restrict__ wlf, short* __restrict__ wrf,
                           short* __restrict__ wef, short* __restrict__ updf,
                           short* __restrict__ eclsf, short* __restrict__ encf) {
  int i = blockIdx.x * 256 + threadIdx.x;
  if (i < 12 * PREP_SEG) {
    int grp = i / PREP_SEG;
    int r = i % PREP_SEG;
    int kind = grp / 3, l = grp % 3;
    int j = r & 7, lane = (r >> 3) & 63;
    int q = lane & 15, g = lane >> 4;
    if (kind < 3) {  // wl/wr/we : [64,256], out cols c = w*64+t*16+q
      int kh = (r >> 9) & 1, t = (r >> 10) & 3, w = r >> 12;
      int k = kh * 32 + g * 8 + j, c = w * 64 + t * 16 + q;
      const float* W = (kind == 0 ? cv_wl : kind == 1 ? cv_wr : cv_we) + (size_t)l * 64 * 256;
      short* out = (kind == 0 ? wlf : kind == 1 ? wrf : wef) + (size_t)l * PREP_SEG;
      out[r] = f2bf(W[k * 256 + c]);
    } else {        // folded update: Wfold[h*64+kk][c] = 0.25*wl[kk][h*64+c], K=256, Ncol=64
      int kh = (r >> 9) & 7, w = r >> 12;
      int k = kh * 32 + g * 8 + j, c = w * 16 + q;
      const float* W = cv_wl + (size_t)l * 64 * 256;
      updf[(size_t)l * PREP_SEG + r] = f2bf(0.25f * W[(k & 63) * 256 + (k >> 6) * 64 + c]);
    }
  } else if (i < 12 * PREP_SEG + 12288) {  // ec_w1 [192,64], 6 k-frags
    int r = i - 12 * PREP_SEG;
    int j = r & 7, lane = (r >> 3) & 63, f = r >> 9;
    int w = f / 6, kh = f % 6;
    int q = lane & 15, g = lane >> 4;
    int k = kh * 32 + g * 8 + j, c = w * 16 + q;
    eclsf[r] = f2bf(ec_w1[(size_t)k * 64 + c]);
  } else {                                  // ee_w2 [64,64], 2 k-frags
    int r = i - 12 * PREP_SEG - 12288;
    if (r >= 4096) return;
    int j = r & 7, lane = (r >> 3) & 63, f = r >> 9;
    int w = f >> 1, kh = f & 1;
    int q = lane & 15, g = lane >> 4;
    int k = kh * 32 + g * 8 + j, c = w * 16 + q;
    encf[r] = f2bf(ee_w2[(size_t)k * 64 + c]);
  }
}

// ---------------- CSR build ----------------

__global__ void k_zero(int* __restrict__ cnt, int* __restrict__ fill) {
  int i = blockIdx.x * blockDim.x + threadIdx.x;
  if (i < N_NODES) { cnt[i] = 0; fill[i] = 0; }
}

__global__ void k_count(const int* __restrict__ dst, int* __restrict__ cnt) {
  int i = blockIdx.x * blockDim.x + threadIdx.x;
  if (i < N_EDGES) atomicAdd(&cnt[dst[i]], 1);
}

__global__ void k_scan1(const int* __restrict__ cnt, int* __restrict__ row_ptr,
                        int* __restrict__ bsum) {
  __shared__ int sh[256];
  int t = threadIdx.x, b = blockIdx.x, i = b * 256 + t;
  int v = (i < N_NODES) ? cnt[i] + 1 : 0;  // +1 self loop
  sh[t] = v;
  __syncthreads();
#pragma unroll
  for (int off = 1; off < 256; off <<= 1) {
    int x = (t >= off) ? sh[t - off] : 0;
    __syncthreads();
    sh[t] += x;
    __syncthreads();
  }
  if (i < N_NODES) row_ptr[i + 1] = sh[t];
  if (t == 255) bsum[b] = sh[255];
}

__global__ void k_scan2(const int* __restrict__ bsum, int* __restrict__ boff) {
  __shared__ int sh[256];
  int t = threadIdx.x;
  int v = (t < NBLK) ? bsum[t] : 0;
  sh[t] = v;
  __syncthreads();
#pragma unroll
  for (int off = 1; off < 256; off <<= 1) {
    int x = (t >= off) ? sh[t - off] : 0;
    __syncthreads();
    sh[t] += x;
    __syncthreads();
  }
  if (t < NBLK) boff[t] = sh[t] - v;  // exclusive
}

__global__ void k_scan3(const int* __restrict__ boff, int* __restrict__ row_ptr) {
  int t = threadIdx.x, b = blockIdx.x, i = b * 256 + t;
  if (i < N_NODES) row_ptr[i + 1] += boff[b];
  if (i == 0) row_ptr[0] = 0;
}

__global__ void k_scatter(const int* __restrict__ dst, const int* __restrict__ row_ptr,
                          int* __restrict__ fill, int* __restrict__ col_idx,
                          int* __restrict__ pdst) {
  int i = blockIdx.x * blockDim.x + threadIdx.x;
  if (i >= EP) return;
  int d = (i < N_EDGES) ? dst[i] : (i - N_EDGES);
  int p = row_ptr[d] + atomicAdd(&fill[d], 1);
  col_idx[p] = i;
  pdst[p] = d;
}

__global__ void k_sort(const int* __restrict__ row_ptr, int* __restrict__ col_idx) {
  int n = blockIdx.x * blockDim.x + threadIdx.x;
  if (n >= N_NODES) return;
  int s = row_ptr[n], e = row_ptr[n + 1];
  for (int i = s + 1; i < e; ++i) {
    int v = col_idx[i];
    int j = i - 1;
    while (j >= s && col_idx[j] > v) { col_idx[j + 1] = col_idx[j]; --j; }
    col_idx[j + 1] = v;
  }
}

// after sort: psrc[p] = source node of CSR slot p; pos[eid] = CSR slot of edge eid
__global__ void k_psrc(const int* __restrict__ col_idx, const int* __restrict__ pdst,
                       const int* __restrict__ src, int* __restrict__ psrc,
                       int* __restrict__ pos) {
  int p = blockIdx.x * 256 + threadIdx.x;
  if (p >= EP) return;
  int eid = col_idx[p];
  pos[eid] = p;
  psrc[p] = (eid < N_EDGES) ? src[eid] : (eid - N_EDGES);
}

// ---------------- encoders ----------------

__global__ __launch_bounds__(256) void k_node_enc(
    const float* __restrict__ x, const float* __restrict__ w1, const float* __restrict__ b1,
    const float* __restrict__ w2, const float* __restrict__ b2,
    float* __restrict__ h, short* __restrict__ hb) {
  __shared__ float w2l[4096];
  int tid = threadIdx.x;
#pragma unroll
  for (int q = 0; q < 16; ++q) w2l[q * 256 + tid] = w2[q * 256 + tid];
  __syncthreads();
  int lane = tid & 63, g = tid >> 6;
  int n = blockIdx.x * 4 + g;
  float x0 = x[n * 2], x1 = x[n * 2 + 1];
  float hid = fmaxf(x0 * w1[lane] + x1 * w1[64 + lane] + b1[lane], 0.f);
  float out = b2[lane];
#pragma unroll
  for (int k = 0; k < 64; ++k) out += bcast(hid, k) * w2l[k * 64 + lane];
  h[n * 64 + lane] = out;
  hb[n * 64 + lane] = f2bf(out);
}

// 64 edges/block: per-wave 16 edges. Layer1 VALU -> private LDS region;
// layer2 MFMA (all 64 cols per wave); LDS-staged 128B row scatter into efc.
__global__ __launch_bounds__(256) void k_edge_enc(
    const float* __restrict__ ea, const float* __restrict__ w1, const float* __restrict__ b1,
    const short* __restrict__ encf, const float* __restrict__ b2,
    const int* __restrict__ pos, short* __restrict__ efc) {
  __shared__ short hs[64 * 72];
  __shared__ short ot[64 * 64];
  __shared__ int ps[64];
  int tid = threadIdx.x;
  int w = tid >> 6, lane = tid & 63, q = lane & 15, g = lane >> 4;
  int e0 = blockIdx.x * 64;
  if (tid < 64) ps[tid] = pos[e0 + tid];
  float w1a = w1[lane], w1b = w1[64 + lane], w1c = w1[128 + lane], b1v = b1[lane];
#pragma unroll
  for (int t = 0; t < 16; ++t) {
    int e = w * 16 + t;
    float a0 = ea[(size_t)(e0 + e) * 3];
    float a1 = ea[(size_t)(e0 + e) * 3 + 1];
    float a2 = ea[(size_t)(e0 + e) * 3 + 2];
    float hid = fmaxf(a0 * w1a + a1 * w1b + a2 * w1c + b1v, 0.f);
    hs[e * 72 + lane] = f2bf(hid);
  }
  // wave-private region: write->read same wave, no barrier needed
  bf16x8 A0 = *(const bf16x8*)&hs[(w * 16 + q) * 72 + g * 8];
  bf16x8 A1 = *(const bf16x8*)&hs[(w * 16 + q) * 72 + 32 + g * 8];
#pragma unroll
  for (int cc = 0; cc < 4; ++cc) {
    bf16x8 B0 = *(const bf16x8*)(encf + ((size_t)(cc * 2 + 0) * 64 + lane) * 8);
    bf16x8 B1 = *(const bf16x8*)(encf + ((size_t)(cc * 2 + 1) * 64 + lane) * 8);
    f32x4 z = {0.f, 0.f, 0.f, 0.f};
    z = mfma16(A0, B0, z);
    z = mfma16(A1, B1, z);
    float bv = b2[cc * 16 + q];
#pragma unroll
    for (int r = 0; r < 4; ++r)
      ot[(w * 16 + g * 4 + r) * 64 + cc * 16 + q] = f2bf(z[r] + bv);
  }
  __syncthreads();
  int row = tid >> 2, part = tid & 3;
  short* d = efc + (size_t)ps[row] * 64 + part * 16;
  const short* s = ot + row * 64 + part * 16;
  *(bf16x8*)d = *(const bf16x8*)s;
  *(bf16x8*)(d + 8) = *(const bf16x8*)(s + 8);
}

// self-loop row (last CSR slot per node) = mean of node's original-edge rows; 8-row parallel
__global__ __launch_bounds__(256) void k_loop_feat(
    const int* __restrict__ row_ptr, short* __restrict__ efc) {
  int tid = threadIdx.x, lane = tid & 63, w = tid >> 6;
  int n = blockIdx.x * 4 + w;
  int s = row_ptr[n], e1 = row_ptr[n + 1];
  int r8 = lane >> 3, oct = lane & 7;
  float acc[8];
#pragma unroll
  for (int j = 0; j < 8; ++j) acc[j] = 0.f;
  for (int p0 = s; p0 < e1 - 1; p0 += 8) {
    int p = p0 + r8;
    if (p < e1 - 1) {
      bf16x8 A = *(const bf16x8*)(efc + (size_t)p * 64 + oct * 8);
#pragma unroll
      for (int j = 0; j < 8; ++j) acc[j] += b2f(A[j]);
    }
  }
#pragma unroll
  for (int j = 0; j < 8; ++j) {
    acc[j] += __shfl_xor(acc[j], 8, 64);
    acc[j] += __shfl_xor(acc[j], 16, 64);
    acc[j] += __shfl_xor(acc[j], 32, 64);
  }
  int c = e1 - 1 - s;
  float invc = 1.f / (float)(c > 0 ? c : 1);
  if (lane < 8) {
    bf16x8 o8;
#pragma unroll
    for (int j = 0; j < 8; ++j) o8[j] = f2bf(acc[j] * invc);
    *(bf16x8*)(efc + (size_t)(e1 - 1) * 64 + lane * 8) = o8;
  }
}

// ---------------- GAT layer ----------------

// 96 CSR slots/block (6 tiles of 16). Gather-to-LDS staging via global_load_lds
// (per-lane global src, XOR-preswizzled cols); single barrier; 4 waves (1/head)
// compute all tiles from LDS with swizzled ds_read_b128.
// LDS tile layout: byte(r,e,c16) = t*6144 + r*2048 + e*128 + c16*16,
// holding global col16 (c16 ^ (e&7)) of row r of edge e.
__global__ __launch_bounds__(256) void k_elog(
    const short* __restrict__ hb, const short* __restrict__ efc,
    const int* __restrict__ psrc, const int* __restrict__ pdst,
    const short* __restrict__ wlf, const short* __restrict__ wrf,
    const short* __restrict__ wef, const float* __restrict__ bl,
    const float* __restrict__ br, const float* __restrict__ att, float* __restrict__ lg) {
  __shared__ __align__(16) short smA[96 * 3 * 64];  // 36 KB
  int tid = threadIdx.x;
  int w = tid >> 6, lane = tid & 63, q = lane & 15, g = lane >> 4;
  int cbase = w * 64;
  int pb = blockIdx.x * 96;

  // ---- staging: wave w issues 9 x 1KB gather-to-LDS ----
  int id9[9];
#pragma unroll
  for (int j = 0; j < 9; ++j) {
    int s = (w * 9 + j) * 64 + lane;      // 16B slot 0..2303
    int t = s / 384, s2 = s - t * 384;
    int r = s2 >> 7, e = (s2 >> 3) & 15;
    int pe = pb + t * 16 + e;
    id9[j] = (r == 0) ? psrc[pe] : (r == 1) ? pdst[pe] : pe;
  }
#pragma unroll
  for (int j = 0; j < 9; ++j) {
    int s = (w * 9 + j) * 64 + lane;
    int t = s / 384, s2 = s - t * 384;
    int r = s2 >> 7, e = (s2 >> 3) & 15, c16 = s2 & 7;
    int cs = (c16 ^ (e & 7)) * 8;         // pre-swizzled short offset
    const short* gp = ((r == 2) ? efc : hb) + (size_t)id9[j] * 64 + cs;
    gl16(gp, &smA[(size_t)s * 8]);
  }

  // ---- B fragments (overlap with staging latency) ----
  bf16x8 Bl[4][2], Br[4][2], Be[4][2];
  float av[4], bv[4];
#pragma unroll
  for (int t = 0; t < 4; ++t) {
    int c = cbase + t * 16 + q;
    av[t] = att[c];
    bv[t] = bl[c] + br[c];
#pragma unroll
    for (int kh = 0; kh < 2; ++kh) {
      size_t fo = ((size_t)((w * 4 + t) * 2 + kh) * 64 + lane) * 8;
      Bl[t][kh] = *(const bf16x8*)(wlf + fo);
      Br[t][kh] = *(const bf16x8*)(wrf + fo);
      Be[t][kh] = *(const bf16x8*)(wef + fo);
    }
  }
  __syncthreads();  // drains staging vmcnt; all tiles visible

  // ---- compute 6 tiles ----
  int x0 = ((0 + g) ^ (q & 7)) * 8;
  int x1 = ((4 + g) ^ (q & 7)) * 8;
  int rowoff = q * 64;                    // shorts
#pragma unroll 1
  for (int t = 0; t < 6; ++t) {
    const short* base = smA + t * 3072;
    bf16x8 As0 = *(const bf16x8*)(base + rowoff + x0);
    bf16x8 As1 = *(const bf16x8*)(base + rowoff + x1);
    bf16x8 Ar0 = *(const bf16x8*)(base + 1024 + rowoff + x0);
    bf16x8 Ar1 = *(const bf16x8*)(base + 1024 + rowoff + x1);
    bf16x8 Ae0 = *(const bf16x8*)(base + 2048 + rowoff + x0);
    bf16x8 Ae1 = *(const bf16x8*)(base + 2048 + rowoff + x1);
    f32x4 acc[4];
#pragma unroll
    for (int tt = 0; tt < 4; ++tt) {
      f32x4 z = {0.f, 0.f, 0.f, 0.f};
      z = mfma16(As0, Bl[tt][0], z);
      z = mfma16(As1, Bl[tt][1], z);
      z = mfma16(Ar0, Br[tt][0], z);
      z = mfma16(Ar1, Br[tt][1], z);
      z = mfma16(Ae0, Be[tt][0], z);
      acc[tt] = mfma16(Ae1, Be[tt][1], z);
    }
#pragma unroll
    for (int r = 0; r < 4; ++r) {
      float pd = 0.f;
#pragma unroll
      for (int tt = 0; tt < 4; ++tt) {
        float m = acc[tt][r] + bv[tt];
        m = m > 0.f ? m : 0.2f * m;
        pd += m * av[tt];
      }
      pd += __shfl_xor(pd, 1, 64);
      pd += __shfl_xor(pd, 2, 64);
      pd += __shfl_xor(pd, 4, 64);
      pd += __shfl_xor(pd, 8, 64);
      if (q == 0) lg[(size_t)(pb + t * 16 + g * 4 + r) * 4 + w] = pd;
    }
  }
}

// per dst node (1 wave/node, 4 nodes/block): softmax (all 4 heads) + single-gather
// aggregation serving all heads -> aggb[n][h*64+k]
__global__ __launch_bounds__(256) void k_agg(
    const short* __restrict__ hb, const float* __restrict__ lg,
    const int* __restrict__ row_ptr, const int* __restrict__ psrc,
    short* __restrict__ aggb) {
  int tid = threadIdx.x, lane = tid & 63, w = tid >> 6;
  int n = blockIdx.x * 4 + w;
  int s0 = row_ptr[n], s1 = row_ptr[n + 1];
  int h4 = lane >> 4, i16 = lane & 15;
  float m = -3.4e38f;
  for (int p = s0 + i16; p < s1; p += 16) m = fmaxf(m, lg[(size_t)p * 4 + h4]);
#pragma unroll
  for (int o = 1; o < 16; o <<= 1) m = fmaxf(m, __shfl_xor(m, o, 64));
  float sum = 0.f;
  for (int p = s0 + i16; p < s1; p += 16) sum += __expf(lg[(size_t)p * 4 + h4] - m);
#pragma unroll
  for (int o = 1; o < 16; o <<= 1) sum += __shfl_xor(sum, o, 64);
  float inv = 1.f / sum;
  float mh[4], ih[4];
#pragma unroll
  for (int h = 0; h < 4; ++h) {
    mh[h] = __shfl(m, h * 16, 64);
    ih[h] = __shfl(inv, h * 16, 64);
  }
  int e8 = lane >> 3, oct = lane & 7;
  float acc[4][8];
#pragma unroll
  for (int h = 0; h < 4; ++h)
#pragma unroll
    for (int j = 0; j < 8; ++j) acc[h][j] = 0.f;
  for (int p0 = s0; p0 < s1; p0 += 8) {
    int p = p0 + e8;
    bool v = p < s1;
    int pc = v ? p : s1 - 1;
    int sp = psrc[pc];
    float4 L = *(const float4*)(lg + (size_t)pc * 4);
    bf16x8 A = *(const bf16x8*)(hb + (size_t)sp * 64 + oct * 8);
    float al[4];
    al[0] = v ? __expf(L.x - mh[0]) * ih[0] : 0.f;
    al[1] = v ? __expf(L.y - mh[1]) * ih[1] : 0.f;
    al[2] = v ? __expf(L.z - mh[2]) * ih[2] : 0.f;
    al[3] = v ? __expf(L.w - mh[3]) * ih[3] : 0.f;
#pragma unroll
    for (int h = 0; h < 4; ++h)
#pragma unroll
      for (int j = 0; j < 8; ++j) acc[h][j] += al[h] * b2f(A[j]);
  }
#pragma unroll
  for (int h = 0; h < 4; ++h)
#pragma unroll
    for (int j = 0; j < 8; ++j) {
      acc[h][j] += __shfl_xor(acc[h][j], 8, 64);
      acc[h][j] += __shfl_xor(acc[h][j], 16, 64);
      acc[h][j] += __shfl_xor(acc[h][j], 32, 64);
    }
  if (lane < 8) {
#pragma unroll
    for (int h = 0; h < 4; ++h) {
      bf16x8 o8;
#pragma unroll
      for (int j = 0; j < 8; ++j) o8[j] = f2bf(acc[h][j]);
      *(bf16x8*)(aggb + (size_t)n * 256 + h * 64 + lane * 8) = o8;
    }
  }
}

// h += relu(aggb @ Wfold + bfold); hb = bf16(h). 16 nodes/block, wave w -> cols w*16..+16
__global__ __launch_bounds__(256) void k_upd(
    const short* __restrict__ aggb, const short* __restrict__ updf,
    const float* __restrict__ bl, const float* __restrict__ bias,
    float* __restrict__ h, short* __restrict__ hb) {
  int tid = threadIdx.x;
  int w = tid >> 6, lane = tid & 63, q = lane & 15, g = lane >> 4;
  int n0 = blockIdx.x * 16;
  const short* arow = aggb + (size_t)(n0 + q) * 256;
  f32x4 z = {0.f, 0.f, 0.f, 0.f};
#pragma unroll
  for (int kh = 0; kh < 8; ++kh) {
    bf16x8 A = *(const bf16x8*)(arow + kh * 32 + g * 8);
    bf16x8 B = *(const bf16x8*)(updf + ((size_t)(w * 8 + kh) * 64 + lane) * 8);
    z = mfma16(A, B, z);
  }
  int c = w * 16 + q;
  float bf = 0.25f * (bl[c] + bl[64 + c] + bl[128 + c] + bl[192 + c]) + bias[c];
#pragma unroll
  for (int r = 0; r < 4; ++r) {
    int n = n0 + g * 4 + r;
    float nh = h[(size_t)n * 64 + c] + fmaxf(z[r] + bf, 0.f);
    h[(size_t)n * 64 + c] = nh;
    hb[(size_t)n * 64 + c] = f2bf(nh);
  }
}

// ---------------- output heads ----------------

// 64 edges/block (4 tiles), pipelined A gathers, single barrier.
__global__ __launch_bounds__(256) void k_ecls(
    const short* __restrict__ hb, const short* __restrict__ efc,
    const int* __restrict__ src, const int* __restrict__ dst,
    const int* __restrict__ pos, const short* __restrict__ eclsf,
    const float* __restrict__ b1, const float* __restrict__ w2,
    const float* __restrict__ b2, float* __restrict__ out) {
  __shared__ float sm[256];
  int tid = threadIdx.x;
  int w = tid >> 6, lane = tid & 63, q = lane & 15, g = lane >> 4;
  int c = w * 16 + q;
  bf16x8 Bf[6];
#pragma unroll
  for (int kh = 0; kh < 6; ++kh)
    Bf[kh] = *(const bf16x8*)(eclsf + ((size_t)(w * 6 + kh) * 64 + lane) * 8);
  float b1v = b1[c], w2v = w2[c], b2v = b2[0];
  int e0b = blockIdx.x * 64;
  int sq[4], dq[4], pq[4];
#pragma unroll
  for (int t = 0; t < 4; ++t) {
    int e = e0b + t * 16 + q;
    sq[t] = src[e];
    dq[t] = dst[e];
    pq[t] = pos[e];
  }
  bf16x8 A[2][6];
#define LOADE(buf, tl) {                                          \
    const short* hs_ = hb + (size_t)sq[tl] * 64;                  \
    const short* hd_ = hb + (size_t)dq[tl] * 64;                  \
    const short* ee_ = efc + (size_t)pq[tl] * 64;                 \
    A[buf][0] = *(const bf16x8*)(hs_ + g * 8);                    \
    A[buf][1] = *(const bf16x8*)(hs_ + 32 + g * 8);               \
    A[buf][2] = *(const bf16x8*)(hd_ + g * 8);                    \
    A[buf][3] = *(const bf16x8*)(hd_ + 32 + g * 8);               \
    A[buf][4] = *(const bf16x8*)(ee_ + g * 8);                    \
    A[buf][5] = *(const bf16x8*)(ee_ + 32 + g * 8);               \
  }
  LOADE(0, 0)
#pragma unroll
  for (int tile = 0; tile < 4; ++tile) {
    const int buf = tile & 1;
    if (tile < 3) LOADE(buf ^ 1, tile + 1)
    f32x4 acc = {0.f, 0.f, 0.f, 0.f};
    acc = mfma16(A[buf][0], Bf[0], acc);
    acc = mfma16(A[buf][1], Bf[1], acc);
    acc = mfma16(A[buf][2], Bf[2], acc);
    acc = mfma16(A[buf][3], Bf[3], acc);
    acc = mfma16(A[buf][4], Bf[4], acc);
    acc = mfma16(A[buf][5], Bf[5], acc);
#pragma unroll
    for (int r = 0; r < 4; ++r) {
      float hv = fmaxf(acc[r] + b1v, 0.f) * w2v;
      hv += __shfl_xor(hv, 1, 64);
      hv += __shfl_xor(hv, 2, 64);
      hv += __shfl_xor(hv, 4, 64);
      hv += __shfl_xor(hv, 8, 64);
      if (q == 0) sm[tile * 64 + w * 16 + g * 4 + r] = hv;
    }
  }
#undef LOADE
  __syncthreads();
  if (tid < 64) {
    int tile = tid >> 4, e = tid & 15;
    float t = sm[tile * 64 + e] + sm[tile * 64 + 16 + e] +
              sm[tile * 64 + 32 + e] + sm[tile * 64 + 48 + e] + b2v;
    out[e0b + tile * 16 + e] = 1.f / (1.f + __expf(-t));
  }
}

__global__ __launch_bounds__(256) void k_offset(
    const float* __restrict__ h, const float* __restrict__ w1, const float* __restrict__ b1,
    const float* __restrict__ w2, const float* __restrict__ b2, float* __restrict__ out) {
  __shared__ float w1l[4096];
  int tid = threadIdx.x;
#pragma unroll
  for (int q = 0; q < 16; ++q) w1l[q * 256 + tid] = w1[q * 256 + tid];
  __syncthreads();
  int lane = tid & 63, g = tid >> 6;
  int n = blockIdx.x * 4 + g;
  float hr = h[n * 64 + lane];
  float hid = b1[lane];
#pragma unroll
  for (int k = 0; k < 64; ++k) hid += bcast(hr, k) * w1l[k * 64 + lane];
  hid = fmaxf(hid, 0.f);
  float p0 = wred_sum(hid * w2[lane * 2]);
  float p1 = wred_sum(hid * w2[lane * 2 + 1]);
  if (lane == 0) {
    out[N_EDGES + n * 2] = p0 + b2[0];
    out[N_EDGES + n * 2 + 1] = p1 + b2[1];
  }
}

// ---------------- launcher ----------------

extern "C" void kernel_launch(void* const* d_in, const int* in_sizes, int n_in,
                              void* d_out, int out_size, void* d_ws, size_t ws_size,
                              hipStream_t stream) {
  const float* x     = (const float*)d_in[0];
  const int*   eidx  = (const int*)d_in[1];
  const float* eattr = (const float*)d_in[2];
  const float* ne_w1 = (const float*)d_in[3];
  const float* ne_b1 = (const float*)d_in[4];
  const float* ne_w2 = (const float*)d_in[5];
  const float* ne_b2 = (const float*)d_in[6];
  const float* ee_w1 = (const float*)d_in[7];
  const float* ee_b1 = (const float*)d_in[8];
  const float* ee_w2 = (const float*)d_in[9];
  const float* ee_b2 = (const float*)d_in[10];
  const float* cv_wl = (const float*)d_in[11];
  const float* cv_bl = (const float*)d_in[12];
  const float* cv_wr = (const float*)d_in[13];
  const float* cv_br = (const float*)d_in[14];
  const float* cv_we = (const float*)d_in[15];
  const float* cv_att = (const float*)d_in[16];
  const float* cv_bias = (const float*)d_in[17];
  const float* ec_w1 = (const float*)d_in[18];
  const float* ec_b1 = (const float*)d_in[19];
  const float* ec_w2 = (const float*)d_in[20];
  const float* ec_b2 = (const float*)d_in[21];
  const float* or_w1 = (const float*)d_in[22];
  const float* or_b1 = (const float*)d_in[23];
  const float* or_w2 = (const float*)d_in[24];
  const float* or_b2 = (const float*)d_in[25];

  const int* src = eidx;
  const int* dst = eidx + N_EDGES;

  // workspace layout
  float* fws = (float*)d_ws;
  size_t o = 0;
  float* h  = fws + o; o += (size_t)N_NODES * 64;
  float* lg = fws + o; o += (size_t)EP * 4;   // layout [p][4]
  short* sws = (short*)(fws + o);
  size_t so = 0;
  short* hb   = sws + so; so += (size_t)N_NODES * 64;
  short* aggb = sws + so; so += (size_t)N_NODES * 256;
  short* efc  = sws + so; so += (size_t)EP * 64;
  short* wlf  = sws + so; so += 3 * PREP_SEG;
  short* wrf  = sws + so; so += 3 * PREP_SEG;
  short* wef  = sws + so; so += 3 * PREP_SEG;
  short* updf = sws + so; so += 3 * PREP_SEG;
  short* eclsf = sws + so; so += 12288;
  short* encf  = sws + so; so += 4096;
  int* iws = (int*)(sws + so + (so & 1));
  int* row_ptr = iws;
  int* col_idx = iws + (N_NODES + 64);
  int* pdst = col_idx + EP;
  int* psrc = pdst + EP;
  int* pos  = psrc + EP;
  int* cnt  = pos + EP;
  int* fill = cnt + N_NODES;
  int* bsum = fill + N_NODES;
  int* boff = bsum + 128;

  float* out = (float*)d_out;

  // weight fragment prep
  k_prep_all<<<(12 * PREP_SEG + 12288 + 4096 + 255) / 256, 256, 0, stream>>>(
      cv_wl, cv_wr, cv_we, ec_w1, ee_w2, wlf, wrf, wef, updf, eclsf, encf);

  // CSR build
  k_zero<<<(N_NODES + 255) / 256, 256, 0, stream>>>(cnt, fill);
  k_count<<<(N_EDGES + 255) / 256, 256, 0, stream>>>(dst, cnt);
  k_scan1<<<NBLK, 256, 0, stream>>>(cnt, row_ptr, bsum);
  k_scan2<<<1, 256, 0, stream>>>(bsum, boff);
  k_scan3<<<NBLK, 256, 0, stream>>>(boff, row_ptr);
  k_scatter<<<(EP + 255) / 256, 256, 0, stream>>>(dst, row_ptr, fill, col_idx, pdst);
  k_sort<<<(N_NODES + 255) / 256, 256, 0, stream>>>(row_ptr, col_idx);
  k_psrc<<<(EP + 255) / 256, 256, 0, stream>>>(col_idx, pdst, src, psrc, pos);

  // encoders
  k_node_enc<<<N_NODES / 4, 256, 0, stream>>>(x, ne_w1, ne_b1, ne_w2, ne_b2, h, hb);
  k_edge_enc<<<N_EDGES / 64, 256, 0, stream>>>(eattr, ee_w1, ee_b1, encf, ee_b2, pos, efc);
  k_loop_feat<<<N_NODES / 4, 256, 0, stream>>>(row_ptr, efc);

  // 3 GATv2 layers
  for (int l = 0; l < 3; ++l) {
    const float* bl = cv_bl + (size_t)l * 256;
    const float* br = cv_br + (size_t)l * 256;
    const float* at = cv_att + (size_t)l * 256;
    const float* bi = cv_bias + (size_t)l * 64;
    k_elog<<<EP / 96, 256, 0, stream>>>(hb, efc, psrc, pdst,
                                        wlf + (size_t)l * PREP_SEG,
                                        wrf + (size_t)l * PREP_SEG,
                                        wef + (size_t)l * PREP_SEG, bl, br, at, lg);
    k_agg<<<N_NODES / 4, 256, 0, stream>>>(hb, lg, row_ptr, psrc, aggb);
    k_upd<<<N_NODES / 16, 256, 0, stream>>>(aggb, updf + (size_t)l * PREP_SEG, bl, bi, h, hb);
  }

  // heads
  k_ecls<<<N_EDGES / 64, 256, 0, stream>>>(hb, efc, src, dst, pos, eclsf,
                                           ec_b1, ec_w2, ec_b2, out);
  k_offset<<<N_NODES / 4, 256, 0, stream>>>(h, or_w1, or_b1, or_w2, or_b2, out);
}